// Round 2
// baseline (5008.297 us; speedup 1.0000x reference)
//
#include <hip/hip_runtime.h>

#define NN 80000     // nodes
#define NE 800000    // edges
#define EH 400000    // first half -> in_w
#define NR 400       // relations
#define DD 256       // feature dim
#define NFP 260      // padded freq row stride in floats (129 complex bins = 258 used)
#define KT 772       // 258 + 258 + 256 GEMM K
#define PI2 6.283185307179586f

// rfft of 256-real rows via per-thread complex rotation. 128 threads/row.
// out row layout: [Re0,Im0,Re1,Im1,...,Re128,Im128] (258 floats, stride NFP)
__global__ void k_rfft(const float* __restrict__ A, float* __restrict__ C) {
  __shared__ float As[DD];
  int row = blockIdx.x;
  int tid = threadIdx.x;               // 128
  As[tid]       = A[(size_t)row * DD + tid];
  As[tid + 128] = A[(size_t)row * DD + tid + 128];
  __syncthreads();
  int k = tid;
  float th = -PI2 * (float)k * (1.0f / 256.0f);
  float wr = cosf(th), wi = sinf(th);
  float zr = 1.0f, zi = 0.0f;
  float ar = 0.0f, ai = 0.0f, a128 = 0.0f;
#pragma unroll 4
  for (int j = 0; j < DD; j += 2) {
    float a0 = As[j], a1 = As[j + 1];
    ar += a0 * zr; ai += a0 * zi;
    float nzr = zr * wr - zi * wi, nzi = zr * wi + zi * wr;
    ar += a1 * nzr; ai += a1 * nzi;
    zr = nzr * wr - nzi * wi; zi = nzr * wi + nzi * wr;
    a128 += a0 - a1;                   // Re at Nyquist: sum a_j*(-1)^j
  }
  float* out = C + (size_t)row * NFP;
  out[2 * k]     = ar;
  out[2 * k + 1] = ai;
  if (tid == 0) { out[256] = a128; out[257] = 0.0f; }
}

// Mcat rows 0..515: row t = (a_k/768) * [cos|-sin](2*pi*j*k/256) dot W[j][c]
__global__ void k_build_m(const float* __restrict__ in_w, const float* __restrict__ out_w,
                          float* __restrict__ Mcat) {
  int t = blockIdx.x;                  // 0..515
  int c = threadIdx.x;                 // 0..255
  const float* W = (t < 258) ? in_w : out_w;
  int tp = (t < 258) ? t : t - 258;
  int k = tp >> 1, im = tp & 1;
  float a = (k == 0 || k == 128) ? 1.0f : 2.0f;
  float scale = a * (1.0f / (256.0f * 3.0f));
  float th = -PI2 * (float)k * (1.0f / 256.0f);
  float wr = cosf(th), wi = sinf(th);
  float zr = 1.0f, zi = 0.0f;
  float acc = 0.0f;
  for (int j = 0; j < DD; ++j) {
    float coef = im ? zi : zr;         // zr=cos(theta_jk), zi=-sin(theta_jk)
    acc += coef * W[(size_t)j * DD + c];
    float nzr = zr * wr - zi * wi; zi = zr * wi + zi * wr; zr = nzr;
  }
  Mcat[(size_t)t * DD + c] = scale * acc;
}

// Mcat rows 516..771 (self-loop): Q[j][c] = (1/3) sum_k lr[(j+k)%256] * loop_w[k][c]
__global__ void k_build_q(const float* __restrict__ lr, const float* __restrict__ loop_w,
                          float* __restrict__ Mq) {
  __shared__ float L[DD];
  int j = blockIdx.x, c = threadIdx.x;
  L[c] = lr[c];
  __syncthreads();
  float acc = 0.0f;
  for (int k2 = 0; k2 < DD; ++k2)
    acc += L[(j + k2) & 255] * loop_w[(size_t)k2 * DD + c];
  Mq[(size_t)j * DD + c] = acc * (1.0f / 3.0f);
}

// one wave per edge: z = conj(xf[src]) * rf[type] * norm, atomically into TF[dst]
__global__ void k_edge(const float* __restrict__ xf, const float* __restrict__ rf,
                       const int* __restrict__ esrc, const int* __restrict__ edst,
                       const int* __restrict__ etyp, const float* __restrict__ enorm,
                       float* __restrict__ TFin, float* __restrict__ TFout) {
  int wave = threadIdx.x >> 6, lane = threadIdx.x & 63;
  int e = blockIdx.x * 4 + wave;
  int s = esrc[e], d = edst[e], r = etyp[e];
  float nm = enorm[e];
  const float4* xp = (const float4*)(xf + (size_t)s * NFP);
  const float4* rp = (const float4*)(rf + (size_t)r * NFP);
  float* tp = ((e < EH) ? TFin : TFout) + (size_t)d * NFP;
  float4 xv = xp[lane];
  float4 rv = rp[lane];
  atomicAdd(tp + 4 * lane + 0, (xv.x * rv.x + xv.y * rv.y) * nm);
  atomicAdd(tp + 4 * lane + 1, (xv.x * rv.y - xv.y * rv.x) * nm);
  atomicAdd(tp + 4 * lane + 2, (xv.z * rv.z + xv.w * rv.w) * nm);
  atomicAdd(tp + 4 * lane + 3, (xv.z * rv.w - xv.w * rv.z) * nm);
  if (lane == 0) {
    float xr = xf[(size_t)s * NFP + 256], xi = xf[(size_t)s * NFP + 257];
    float rr = rf[(size_t)r * NFP + 256], ri = rf[(size_t)r * NFP + 257];
    atomicAdd(tp + 256, (xr * rr + xi * ri) * nm);
    atomicAdd(tp + 257, (xr * ri - xi * rr) * nm);
  }
}

// out_pre[v][c] = sum_k Z[v][k]*Mcat[k][c] + bias[c] ; Z = [TFin | TFout | x]
// writes f32 to dout, accumulates per-channel sum/sumsq for BN
__global__ __launch_bounds__(256) void k_gemm(
    const float* __restrict__ TFin, const float* __restrict__ TFout,
    const float* __restrict__ x, const float* __restrict__ Mcat,
    const float* __restrict__ bias, float* __restrict__ dout,
    float* __restrict__ sum1, float* __restrict__ sum2) {
  __shared__ float As[64][16];
  __shared__ float Bs[16][DD];
  int tid = threadIdx.x;
  int v0 = blockIdx.x * 64;
  int rg = tid >> 6;                   // wave id: rows rg*16..rg*16+15
  int cg = tid & 63;                   // cols cg*4..cg*4+3
  float acc[16][4];
#pragma unroll
  for (int i = 0; i < 16; ++i)
    for (int j = 0; j < 4; ++j) acc[i][j] = 0.0f;

  for (int k0 = 0; k0 < KT; k0 += 16) {
    for (int i = tid; i < 64 * 16; i += 256) {
      int rr = i >> 4, kk = i & 15;
      int gk = k0 + kk;
      int v = v0 + rr;
      float val;
      if (gk < 258)      val = TFin[(size_t)v * NFP + gk];
      else if (gk < 516) val = TFout[(size_t)v * NFP + gk - 258];
      else if (gk < KT)  val = x[(size_t)v * DD + gk - 516];
      else               val = 0.0f;
      As[rr][kk] = val;
    }
    for (int i = tid; i < 16 * DD; i += 256) {
      int kk = i >> 8, c = i & 255;
      int gk = k0 + kk;
      Bs[kk][c] = (gk < KT) ? Mcat[(size_t)gk * DD + c] : 0.0f;
    }
    __syncthreads();
#pragma unroll
    for (int kk = 0; kk < 16; ++kk) {
      float4 b = *(const float4*)&Bs[kk][cg * 4];
#pragma unroll
      for (int i = 0; i < 16; ++i) {
        float a = As[rg * 16 + i][kk];
        acc[i][0] += a * b.x; acc[i][1] += a * b.y;
        acc[i][2] += a * b.z; acc[i][3] += a * b.w;
      }
    }
    __syncthreads();
  }

  float bc[4];
#pragma unroll
  for (int j = 0; j < 4; ++j) bc[j] = bias[cg * 4 + j];
  float s1[4] = {0, 0, 0, 0}, s2[4] = {0, 0, 0, 0};
#pragma unroll
  for (int i = 0; i < 16; ++i) {
    int v = v0 + rg * 16 + i;
    float4 o;
    float vl[4];
#pragma unroll
    for (int j = 0; j < 4; ++j) {
      vl[j] = acc[i][j] + bc[j];
      s1[j] += vl[j];
      s2[j] += vl[j] * vl[j];
    }
    o.x = vl[0]; o.y = vl[1]; o.z = vl[2]; o.w = vl[3];
    *(float4*)(dout + (size_t)v * DD + cg * 4) = o;
  }
#pragma unroll
  for (int j = 0; j < 4; ++j) {
    atomicAdd(&sum1[cg * 4 + j], s1[j]);
    atomicAdd(&sum2[cg * 4 + j], s2[j]);
  }
}

__global__ void k_stats(const float* __restrict__ sum1, const float* __restrict__ sum2,
                        float* __restrict__ mean, float* __restrict__ rstd) {
  int c = threadIdx.x;
  float m = sum1[c] * (1.0f / (float)NN);
  float var = sum2[c] * (1.0f / (float)NN) - m * m;
  mean[c] = m;
  rstd[c] = rsqrtf(var + 1e-5f);
}

__global__ void k_norm(float* __restrict__ out, const float* __restrict__ mean,
                       const float* __restrict__ rstd) {
  size_t i4 = ((size_t)blockIdx.x * 256 + threadIdx.x) * 4;
  float4* p = (float4*)(out + i4);
  float4 v = *p;
  int c0 = (int)(i4 & 255);
  v.x = (v.x - mean[c0 + 0]) * rstd[c0 + 0];
  v.y = (v.y - mean[c0 + 1]) * rstd[c0 + 1];
  v.z = (v.z - mean[c0 + 2]) * rstd[c0 + 2];
  v.w = (v.w - mean[c0 + 3]) * rstd[c0 + 3];
  *p = v;
}

__global__ void k_rel(const float* __restrict__ rel, const float* __restrict__ wrel,
                      float* __restrict__ out2) {
  __shared__ float R[DD];
  int r = blockIdx.x, c = threadIdx.x;
  R[c] = rel[(size_t)r * DD + c];
  __syncthreads();
  float acc = 0.0f;
  for (int j = 0; j < DD; ++j)
    acc += R[j] * wrel[(size_t)j * DD + c];
  out2[(size_t)r * DD + c] = acc;
}

__global__ void k_fail(float* __restrict__ out, int n) {
  int i = blockIdx.x * 256 + threadIdx.x;
  if (i < n) out[i] = 1.0e6f;   // unambiguous "workspace too small" marker
}

extern "C" void kernel_launch(void* const* d_in, const int* in_sizes, int n_in,
                              void* d_out, int out_size, void* d_ws, size_t ws_size,
                              hipStream_t stream) {
  (void)in_sizes; (void)n_in;
  const float* x      = (const float*)d_in[0];
  const float* rel    = (const float*)d_in[1];
  const int*   esrc   = (const int*)d_in[2];
  const int*   edst   = (const int*)d_in[3];
  const int*   etyp   = (const int*)d_in[4];
  const float* enorm  = (const float*)d_in[5];
  const float* in_w   = (const float*)d_in[6];
  const float* out_w  = (const float*)d_in[7];
  const float* loop_w = (const float*)d_in[8];
  const float* w_rel  = (const float*)d_in[9];
  const float* lr     = (const float*)d_in[10];
  const float* bias   = (const float*)d_in[11];
  float* dout = (float*)d_out;

  float* ws = (float*)d_ws;
  size_t off = 0;
  float* xf    = ws + off; off += (size_t)NN * NFP;
  float* rf    = ws + off; off += (size_t)NR * NFP;
  float* Mcat  = ws + off; off += (size_t)KT * DD;
  float* TFin  = ws + off; off += (size_t)NN * NFP;   // TFin,TFout,sum1,sum2 contiguous (one memset)
  float* TFout = ws + off; off += (size_t)NN * NFP;
  float* sum1  = ws + off; off += DD;
  float* sum2  = ws + off; off += DD;
  float* meanb = ws + off; off += DD;
  float* rstdb = ws + off; off += DD;

  if (ws_size < off * sizeof(float)) {
    k_fail<<<(out_size + 255) / 256, 256, 0, stream>>>(dout, out_size);
    return;
  }

  hipMemsetAsync(TFin, 0, ((size_t)2 * NN * NFP + 2 * DD) * sizeof(float), stream);
  k_rfft<<<NN, 128, 0, stream>>>(x, xf);
  k_rfft<<<NR, 128, 0, stream>>>(rel, rf);
  k_build_m<<<516, 256, 0, stream>>>(in_w, out_w, Mcat);
  k_build_q<<<256, 256, 0, stream>>>(lr, loop_w, Mcat + (size_t)516 * DD);
  k_edge<<<NE / 4, 256, 0, stream>>>(xf, rf, esrc, edst, etyp, enorm, TFin, TFout);
  k_gemm<<<NN / 64, 256, 0, stream>>>(TFin, TFout, x, Mcat, bias, dout, sum1, sum2);
  k_stats<<<1, 256, 0, stream>>>(sum1, sum2, meanb, rstdb);
  k_norm<<<NN * DD / 4 / 256, 256, 0, stream>>>(dout, meanb, rstdb);
  k_rel<<<NR, 256, 0, stream>>>(rel, w_rel, dout + (size_t)NN * DD);
}

// Round 3
// 2226.150 us; speedup vs baseline: 2.2498x; 2.2498x over previous
//
#include <hip/hip_runtime.h>

#define NN 80000     // nodes
#define NE 800000    // edges
#define EH 400000    // first half -> in_w
#define NR 400       // relations
#define DD 256       // feature dim
#define NFP 260      // padded freq row stride (129 complex bins = 258 used)
#define KT 772       // 258 + 258 + 256 GEMM K
#define NB 160000    // sort buckets: dir*NN + dst
#define NCH 157      // ceil(NB/1024) scan chunks
#define PI2 6.283185307179586f

typedef unsigned short u16;

static __device__ __forceinline__ float bu2f(u16 u) {
  return __uint_as_float(((unsigned int)u) << 16);
}
static __device__ __forceinline__ u16 f2bu(float f) {
  unsigned int x = __float_as_uint(f);
  x += 0x7fffu + ((x >> 16) & 1u);   // RNE
  return (u16)(x >> 16);
}

// rfft of 256-real rows via per-thread complex rotation. 128 threads/row.
// out row (bf16): [Re0,Im0,...,Re128,Im128] (258 vals, stride 260 u16 = 520B)
__global__ void k_rfft(const float* __restrict__ A, u16* __restrict__ C) {
  __shared__ float As[DD];
  int row = blockIdx.x;
  int tid = threadIdx.x;               // 128
  As[tid]       = A[(size_t)row * DD + tid];
  As[tid + 128] = A[(size_t)row * DD + tid + 128];
  __syncthreads();
  int k = tid;
  float th = -PI2 * (float)k * (1.0f / 256.0f);
  float wr = cosf(th), wi = sinf(th);
  float zr = 1.0f, zi = 0.0f;
  float ar = 0.0f, ai = 0.0f, a128 = 0.0f;
#pragma unroll 4
  for (int j = 0; j < DD; j += 2) {
    float a0 = As[j], a1 = As[j + 1];
    ar += a0 * zr; ai += a0 * zi;
    float nzr = zr * wr - zi * wi, nzi = zr * wi + zi * wr;
    ar += a1 * nzr; ai += a1 * nzi;
    zr = nzr * wr - nzi * wi; zi = nzr * wi + nzi * wr;
    a128 += a0 - a1;                   // Re at Nyquist
  }
  u16* out = C + (size_t)row * NFP;
  out[2 * k]     = f2bu(ar);
  out[2 * k + 1] = f2bu(ai);
  if (tid == 0) { out[256] = f2bu(a128); out[257] = 0; }
}

// Mcat rows 0..515: row t = (a_k/768) * [cos|-sin](2*pi*j*k/256) dot W[j][c]
__global__ void k_build_m(const float* __restrict__ in_w, const float* __restrict__ out_w,
                          float* __restrict__ Mcat) {
  int t = blockIdx.x;                  // 0..515
  int c = threadIdx.x;                 // 0..255
  const float* W = (t < 258) ? in_w : out_w;
  int tp = (t < 258) ? t : t - 258;
  int k = tp >> 1, im = tp & 1;
  float a = (k == 0 || k == 128) ? 1.0f : 2.0f;
  float scale = a * (1.0f / (256.0f * 3.0f));
  float th = -PI2 * (float)k * (1.0f / 256.0f);
  float wr = cosf(th), wi = sinf(th);
  float zr = 1.0f, zi = 0.0f;
  float acc = 0.0f;
  for (int j = 0; j < DD; ++j) {
    float coef = im ? zi : zr;
    acc += coef * W[(size_t)j * DD + c];
    float nzr = zr * wr - zi * wi; zi = zr * wi + zi * wr; zr = nzr;
  }
  Mcat[(size_t)t * DD + c] = scale * acc;
}

// Mcat rows 516..771 (self-loop): Q[j][c] = (1/3) sum_k lr[(j+k)%256] * loop_w[k][c]
__global__ void k_build_q(const float* __restrict__ lr, const float* __restrict__ loop_w,
                          float* __restrict__ Mq) {
  __shared__ float L[DD];
  int j = blockIdx.x, c = threadIdx.x;
  L[c] = lr[c];
  __syncthreads();
  float acc = 0.0f;
  for (int k2 = 0; k2 < DD; ++k2)
    acc += L[(j + k2) & 255] * loop_w[(size_t)k2 * DD + c];
  Mq[(size_t)j * DD + c] = acc * (1.0f / 3.0f);
}

// ---------- counting sort by key = (e>=EH)*NN + dst ----------
__global__ void k_hist(const int* __restrict__ edst, int* __restrict__ cnt) {
  int e = blockIdx.x * 256 + threadIdx.x;
  int key = edst[e] + ((e >= EH) ? NN : 0);
  atomicAdd(&cnt[key], 1);
}

__global__ __launch_bounds__(256) void k_scan1(const int* __restrict__ cnt,
                                               int* __restrict__ base,
                                               int* __restrict__ chunkTot) {
  __shared__ int wsum[4];
  int t = threadIdx.x;
  int g0 = blockIdx.x * 1024 + t * 4;
  int v[4], ex[4], s = 0;
#pragma unroll
  for (int j = 0; j < 4; ++j) v[j] = (g0 + j < NB) ? cnt[g0 + j] : 0;
#pragma unroll
  for (int j = 0; j < 4; ++j) { ex[j] = s; s += v[j]; }
  int lane = t & 63, w = t >> 6;
  int inc = s;
  for (int off = 1; off < 64; off <<= 1) {
    int n = __shfl_up(inc, off);
    if (lane >= off) inc += n;
  }
  if (lane == 63) wsum[w] = inc;
  __syncthreads();
  int woff = 0;
  for (int i = 0; i < w; ++i) woff += wsum[i];
  int exth = woff + inc - s;           // exclusive offset of this thread in block
#pragma unroll
  for (int j = 0; j < 4; ++j)
    if (g0 + j < NB) base[g0 + j] = exth + ex[j];
  if (t == 255) chunkTot[blockIdx.x] = woff + inc;
}

__global__ __launch_bounds__(256) void k_scan2(const int* __restrict__ chunkTot,
                                               int* __restrict__ chunkOff) {
  __shared__ int wsum[4];
  int t = threadIdx.x;
  int v = (t < NCH) ? chunkTot[t] : 0;
  int lane = t & 63, w = t >> 6;
  int inc = v;
  for (int off = 1; off < 64; off <<= 1) {
    int n = __shfl_up(inc, off);
    if (lane >= off) inc += n;
  }
  if (lane == 63) wsum[w] = inc;
  __syncthreads();
  int woff = 0;
  for (int i = 0; i < w; ++i) woff += wsum[i];
  if (t < NCH) chunkOff[t] = woff + inc - v;
}

__global__ void k_scan3(int* __restrict__ base, const int* __restrict__ chunkOff,
                        int* __restrict__ cursor) {
  int i = blockIdx.x * 256 + threadIdx.x;
  if (i < NB) {
    int b = base[i] + chunkOff[i >> 10];
    base[i] = b;
    cursor[i] = b;
  }
  if (i == 0) base[NB] = NE;
}

__global__ void k_scatter(const int* __restrict__ edst, int* __restrict__ cursor,
                          int* __restrict__ order) {
  int e = blockIdx.x * 256 + threadIdx.x;
  int key = edst[e] + ((e >= EH) ? NN : 0);
  int pos = atomicAdd(&cursor[key], 1);
  order[pos] = e;
}

// one wave per bucket: TF[dst] = sum over bucket edges of conj(xf[src])*rf[type]*norm
__global__ __launch_bounds__(256) void k_reduce(
    const u16* __restrict__ xfh, const u16* __restrict__ rfh,
    const int* __restrict__ order, const int* __restrict__ esrc,
    const int* __restrict__ etyp, const float* __restrict__ enorm,
    const int* __restrict__ base, float* __restrict__ TFin, float* __restrict__ TFout) {
  int w = threadIdx.x >> 6, lane = threadIdx.x & 63;
  int b = blockIdx.x * 4 + w;
  int start = base[b], end = base[b + 1];
  float a0 = 0, a1 = 0, a2 = 0, a3 = 0;
  float nyr = 0, nyi = 0;
  for (int p = start; p < end; ++p) {
    int e = order[p];
    int s = esrc[e], r = etyp[e];
    float nm = enorm[e];
    const u16* xp = xfh + (size_t)s * NFP;
    const u16* rp = rfh + (size_t)r * NFP;
    ushort4 xv = *(const ushort4*)(xp + 4 * lane);
    ushort4 rv = *(const ushort4*)(rp + 4 * lane);
    float xr0 = bu2f(xv.x), xi0 = bu2f(xv.y), xr1 = bu2f(xv.z), xi1 = bu2f(xv.w);
    float rr0 = bu2f(rv.x), ri0 = bu2f(rv.y), rr1 = bu2f(rv.z), ri1 = bu2f(rv.w);
    a0 += (xr0 * rr0 + xi0 * ri0) * nm;
    a1 += (xr0 * ri0 - xi0 * rr0) * nm;
    a2 += (xr1 * rr1 + xi1 * ri1) * nm;
    a3 += (xr1 * ri1 - xi1 * rr1) * nm;
    if (lane == 0) {
      float ar = bu2f(xp[256]), ai = bu2f(xp[257]);
      float br = bu2f(rp[256]), bi = bu2f(rp[257]);
      nyr += (ar * br + ai * bi) * nm;
      nyi += (ar * bi - ai * br) * nm;
    }
  }
  float* tp = (b < NN) ? (TFin + (size_t)b * NFP) : (TFout + (size_t)(b - NN) * NFP);
  float4 o = {a0, a1, a2, a3};
  *(float4*)(tp + 4 * lane) = o;
  if (lane == 0) { tp[256] = nyr; tp[257] = nyi; }
}

// out_pre[v][c] = sum_k Z[v][k]*Mcat[k][c] + bias[c] ; Z = [TFin | TFout | x]
__global__ __launch_bounds__(256) void k_gemm(
    const float* __restrict__ TFin, const float* __restrict__ TFout,
    const float* __restrict__ x, const float* __restrict__ Mcat,
    const float* __restrict__ bias, float* __restrict__ dout,
    float* __restrict__ sum1, float* __restrict__ sum2) {
  __shared__ float As[64][16];
  __shared__ float Bs[16][DD];
  int tid = threadIdx.x;
  int v0 = blockIdx.x * 64;
  int rg = tid >> 6;
  int cg = tid & 63;
  float acc[16][4];
#pragma unroll
  for (int i = 0; i < 16; ++i)
    for (int j = 0; j < 4; ++j) acc[i][j] = 0.0f;

  for (int k0 = 0; k0 < KT; k0 += 16) {
    for (int i = tid; i < 64 * 16; i += 256) {
      int rr = i >> 4, kk = i & 15;
      int gk = k0 + kk;
      int v = v0 + rr;
      float val;
      if (gk < 258)      val = TFin[(size_t)v * NFP + gk];
      else if (gk < 516) val = TFout[(size_t)v * NFP + gk - 258];
      else if (gk < KT)  val = x[(size_t)v * DD + gk - 516];
      else               val = 0.0f;
      As[rr][kk] = val;
    }
    for (int i = tid; i < 16 * DD; i += 256) {
      int kk = i >> 8, c = i & 255;
      int gk = k0 + kk;
      Bs[kk][c] = (gk < KT) ? Mcat[(size_t)gk * DD + c] : 0.0f;
    }
    __syncthreads();
#pragma unroll
    for (int kk = 0; kk < 16; ++kk) {
      float4 b = *(const float4*)&Bs[kk][cg * 4];
#pragma unroll
      for (int i = 0; i < 16; ++i) {
        float a = As[rg * 16 + i][kk];
        acc[i][0] += a * b.x; acc[i][1] += a * b.y;
        acc[i][2] += a * b.z; acc[i][3] += a * b.w;
      }
    }
    __syncthreads();
  }

  float bc[4];
#pragma unroll
  for (int j = 0; j < 4; ++j) bc[j] = bias[cg * 4 + j];
  float s1[4] = {0, 0, 0, 0}, s2[4] = {0, 0, 0, 0};
#pragma unroll
  for (int i = 0; i < 16; ++i) {
    int v = v0 + rg * 16 + i;
    float4 o;
    float vl[4];
#pragma unroll
    for (int j = 0; j < 4; ++j) {
      vl[j] = acc[i][j] + bc[j];
      s1[j] += vl[j];
      s2[j] += vl[j] * vl[j];
    }
    o.x = vl[0]; o.y = vl[1]; o.z = vl[2]; o.w = vl[3];
    *(float4*)(dout + (size_t)v * DD + cg * 4) = o;
  }
#pragma unroll
  for (int j = 0; j < 4; ++j) {
    atomicAdd(&sum1[cg * 4 + j], s1[j]);
    atomicAdd(&sum2[cg * 4 + j], s2[j]);
  }
}

__global__ void k_stats(const float* __restrict__ sum1, const float* __restrict__ sum2,
                        float* __restrict__ mean, float* __restrict__ rstd) {
  int c = threadIdx.x;
  float m = sum1[c] * (1.0f / (float)NN);
  float var = sum2[c] * (1.0f / (float)NN) - m * m;
  mean[c] = m;
  rstd[c] = rsqrtf(var + 1e-5f);
}

__global__ void k_norm(float* __restrict__ out, const float* __restrict__ mean,
                       const float* __restrict__ rstd) {
  size_t i4 = ((size_t)blockIdx.x * 256 + threadIdx.x) * 4;
  float4* p = (float4*)(out + i4);
  float4 v = *p;
  int c0 = (int)(i4 & 255);
  v.x = (v.x - mean[c0 + 0]) * rstd[c0 + 0];
  v.y = (v.y - mean[c0 + 1]) * rstd[c0 + 1];
  v.z = (v.z - mean[c0 + 2]) * rstd[c0 + 2];
  v.w = (v.w - mean[c0 + 3]) * rstd[c0 + 3];
  *p = v;
}

__global__ void k_rel(const float* __restrict__ rel, const float* __restrict__ wrel,
                      float* __restrict__ out2) {
  __shared__ float R[DD];
  int r = blockIdx.x, c = threadIdx.x;
  R[c] = rel[(size_t)r * DD + c];
  __syncthreads();
  float acc = 0.0f;
  for (int j = 0; j < DD; ++j)
    acc += R[j] * wrel[(size_t)j * DD + c];
  out2[(size_t)r * DD + c] = acc;
}

__global__ void k_fail(float* __restrict__ out, int n) {
  int i = blockIdx.x * 256 + threadIdx.x;
  if (i < n) out[i] = 1.0e6f;   // "workspace too small" marker
}

extern "C" void kernel_launch(void* const* d_in, const int* in_sizes, int n_in,
                              void* d_out, int out_size, void* d_ws, size_t ws_size,
                              hipStream_t stream) {
  (void)in_sizes; (void)n_in;
  const float* x      = (const float*)d_in[0];
  const float* rel    = (const float*)d_in[1];
  const int*   esrc   = (const int*)d_in[2];
  const int*   edst   = (const int*)d_in[3];
  const int*   etyp   = (const int*)d_in[4];
  const float* enorm  = (const float*)d_in[5];
  const float* in_w   = (const float*)d_in[6];
  const float* out_w  = (const float*)d_in[7];
  const float* loop_w = (const float*)d_in[8];
  const float* w_rel  = (const float*)d_in[9];
  const float* lr     = (const float*)d_in[10];
  const float* bias   = (const float*)d_in[11];
  float* dout = (float*)d_out;

  float* ws = (float*)d_ws;
  size_t off = 0;
  float* TFin  = ws + off; off += (size_t)NN * NFP;
  float* TFout = ws + off; off += (size_t)NN * NFP;
  float* Mcat  = ws + off; off += (size_t)KT * DD;
  float* sum1  = ws + off; off += DD;
  float* sum2  = ws + off; off += DD;
  float* meanb = ws + off; off += DD;
  float* rstdb = ws + off; off += DD;
  u16*   xfh   = (u16*)(ws + off); off += (size_t)NN * NFP / 2;
  u16*   rfh   = (u16*)(ws + off); off += (size_t)NR * NFP / 2;
  int*   cnt   = (int*)(ws + off); off += NB + 1;
  int*   baseA = (int*)(ws + off); off += NB + 1;
  int*   curA  = (int*)(ws + off); off += NB;
  int*   order = (int*)(ws + off); off += NE;
  int*   chT   = (int*)(ws + off); off += 256;
  int*   chO   = (int*)(ws + off); off += 256;

  if (ws_size < off * sizeof(float)) {
    k_fail<<<(out_size + 255) / 256, 256, 0, stream>>>(dout, out_size);
    return;
  }

  hipMemsetAsync(cnt, 0, (NB + 1) * sizeof(int), stream);
  hipMemsetAsync(sum1, 0, 2 * DD * sizeof(float), stream);
  k_rfft<<<NN, 128, 0, stream>>>(x, xfh);
  k_rfft<<<NR, 128, 0, stream>>>(rel, rfh);
  k_build_m<<<516, 256, 0, stream>>>(in_w, out_w, Mcat);
  k_build_q<<<256, 256, 0, stream>>>(lr, loop_w, Mcat + (size_t)516 * DD);
  k_hist<<<NE / 256, 256, 0, stream>>>(edst, cnt);
  k_scan1<<<NCH, 256, 0, stream>>>(cnt, baseA, chT);
  k_scan2<<<1, 256, 0, stream>>>(chT, chO);
  k_scan3<<<(NB + 255) / 256, 256, 0, stream>>>(baseA, chO, curA);
  k_scatter<<<NE / 256, 256, 0, stream>>>(edst, curA, order);
  k_reduce<<<NB / 4, 256, 0, stream>>>(xfh, rfh, order, esrc, etyp, enorm, baseA,
                                       TFin, TFout);
  k_gemm<<<NN / 64, 256, 0, stream>>>(TFin, TFout, x, Mcat, bias, dout, sum1, sum2);
  k_stats<<<1, 256, 0, stream>>>(sum1, sum2, meanb, rstdb);
  k_norm<<<NN * DD / 4 / 256, 256, 0, stream>>>(dout, meanb, rstdb);
  k_rel<<<NR, 256, 0, stream>>>(rel, w_rel, dout + (size_t)NN * DD);
}

// Round 4
// 1050.282 us; speedup vs baseline: 4.7685x; 2.1196x over previous
//
#include <hip/hip_runtime.h>

#define NN 80000     // nodes
#define NE 800000    // edges
#define EH 400000    // first half -> in_w
#define NR 400       // relations
#define DD 256       // feature dim
#define NFP 260      // freq row stride in bf16 elems (129 complex bins = 258 used)
#define KT 772       // 258 + 258 + 256 logical GEMM K
#define KP 832       // K padded to 13*64
#define NB 160000    // sort buckets: dir*NN + dst
#define NCH 157      // ceil(NB/1024) scan chunks
#define PI2 6.283185307179586f

typedef unsigned short u16;
typedef __attribute__((ext_vector_type(8))) short bf16x8;
typedef __attribute__((ext_vector_type(4))) float f32x4;

static __device__ __forceinline__ float bu2f(u16 u) {
  return __uint_as_float(((unsigned int)u) << 16);
}
static __device__ __forceinline__ u16 f2bu(float f) {
  unsigned int x = __float_as_uint(f);
  x += 0x7fffu + ((x >> 16) & 1u);   // RNE
  return (u16)(x >> 16);
}
static __device__ __forceinline__ unsigned int pk2(float a, float b) {
  return (unsigned int)f2bu(a) | ((unsigned int)f2bu(b) << 16);
}

// rfft of 256-real rows via per-thread complex rotation. 128 threads/row.
__global__ void k_rfft(const float* __restrict__ A, u16* __restrict__ C) {
  __shared__ float As[DD];
  int row = blockIdx.x;
  int tid = threadIdx.x;               // 128
  As[tid]       = A[(size_t)row * DD + tid];
  As[tid + 128] = A[(size_t)row * DD + tid + 128];
  __syncthreads();
  int k = tid;
  float th = -PI2 * (float)k * (1.0f / 256.0f);
  float wr = cosf(th), wi = sinf(th);
  float zr = 1.0f, zi = 0.0f;
  float ar = 0.0f, ai = 0.0f, a128 = 0.0f;
#pragma unroll 4
  for (int j = 0; j < DD; j += 2) {
    float a0 = As[j], a1 = As[j + 1];
    ar += a0 * zr; ai += a0 * zi;
    float nzr = zr * wr - zi * wi, nzi = zr * wi + zi * wr;
    ar += a1 * nzr; ai += a1 * nzi;
    zr = nzr * wr - nzi * wi; zi = nzr * wi + nzi * wr;
    a128 += a0 - a1;
  }
  u16* out = C + (size_t)row * NFP;
  out[2 * k]     = f2bu(ar);
  out[2 * k + 1] = f2bu(ai);
  if (tid == 0) { out[256] = f2bu(a128); out[257] = 0; }
}

// Bt rows: Bt[c][t] = (a_k/768)*[cos|-sin](2*pi*j*k/256) dot W[j][c], t=0..515
__global__ void k_build_m(const float* __restrict__ in_w, const float* __restrict__ out_w,
                          u16* __restrict__ Bt) {
  int t = blockIdx.x;                  // 0..515
  int c = threadIdx.x;                 // 0..255
  const float* W = (t < 258) ? in_w : out_w;
  int tp = (t < 258) ? t : t - 258;
  int k = tp >> 1, im = tp & 1;
  float a = (k == 0 || k == 128) ? 1.0f : 2.0f;
  float scale = a * (1.0f / (256.0f * 3.0f));
  float th = -PI2 * (float)k * (1.0f / 256.0f);
  float wr = cosf(th), wi = sinf(th);
  float zr = 1.0f, zi = 0.0f;
  float acc = 0.0f;
  for (int j = 0; j < DD; ++j) {
    float coef = im ? zi : zr;
    acc += coef * W[(size_t)j * DD + c];
    float nzr = zr * wr - zi * wi; zi = zr * wi + zi * wr; zr = nzr;
  }
  Bt[(size_t)c * KP + t] = f2bu(scale * acc);
}

// Bt[c][516+j] = (1/3) sum_k lr[(j+k)%256] * loop_w[k][c]; also zero K-pad
__global__ void k_build_q(const float* __restrict__ lr, const float* __restrict__ loop_w,
                          u16* __restrict__ Bt) {
  __shared__ float L[DD];
  int j = blockIdx.x, c = threadIdx.x;
  L[c] = lr[c];
  __syncthreads();
  float acc = 0.0f;
  for (int k2 = 0; k2 < DD; ++k2)
    acc += L[(j + k2) & 255] * loop_w[(size_t)k2 * DD + c];
  Bt[(size_t)c * KP + 516 + j] = f2bu(acc * (1.0f / 3.0f));
  if (j < KP - KT) Bt[(size_t)c * KP + KT + j] = 0;
}

// x -> bf16 into Apack cols 516..771, zero cols 772..831
__global__ void k_cvt(const float* __restrict__ x, u16* __restrict__ Ap) {
  int t = threadIdx.x, b = blockIdx.x;  // 625 blocks x 128 rows
  for (int i = 0; i < 128; ++i) {
    size_t r = (size_t)b * 128 + i;
    Ap[r * KP + 516 + t] = f2bu(x[r * DD + t]);
    if (t < KP - KT) Ap[r * KP + KT + t] = 0;
  }
}

// ---------- counting sort by key = (e>=EH)*NN + dst ----------
__global__ void k_hist(const int* __restrict__ edst, int* __restrict__ cnt) {
  int e = blockIdx.x * 256 + threadIdx.x;
  int key = edst[e] + ((e >= EH) ? NN : 0);
  atomicAdd(&cnt[key], 1);
}

__global__ __launch_bounds__(256) void k_scan1(const int* __restrict__ cnt,
                                               int* __restrict__ base,
                                               int* __restrict__ chunkTot) {
  __shared__ int wsum[4];
  int t = threadIdx.x;
  int g0 = blockIdx.x * 1024 + t * 4;
  int v[4], ex[4], s = 0;
#pragma unroll
  for (int j = 0; j < 4; ++j) v[j] = (g0 + j < NB) ? cnt[g0 + j] : 0;
#pragma unroll
  for (int j = 0; j < 4; ++j) { ex[j] = s; s += v[j]; }
  int lane = t & 63, w = t >> 6;
  int inc = s;
  for (int off = 1; off < 64; off <<= 1) {
    int n = __shfl_up(inc, off);
    if (lane >= off) inc += n;
  }
  if (lane == 63) wsum[w] = inc;
  __syncthreads();
  int woff = 0;
  for (int i = 0; i < w; ++i) woff += wsum[i];
  int exth = woff + inc - s;
#pragma unroll
  for (int j = 0; j < 4; ++j)
    if (g0 + j < NB) base[g0 + j] = exth + ex[j];
  if (t == 255) chunkTot[blockIdx.x] = woff + inc;
}

__global__ __launch_bounds__(256) void k_scan2(const int* __restrict__ chunkTot,
                                               int* __restrict__ chunkOff) {
  __shared__ int wsum[4];
  int t = threadIdx.x;
  int v = (t < NCH) ? chunkTot[t] : 0;
  int lane = t & 63, w = t >> 6;
  int inc = v;
  for (int off = 1; off < 64; off <<= 1) {
    int n = __shfl_up(inc, off);
    if (lane >= off) inc += n;
  }
  if (lane == 63) wsum[w] = inc;
  __syncthreads();
  int woff = 0;
  for (int i = 0; i < w; ++i) woff += wsum[i];
  if (t < NCH) chunkOff[t] = woff + inc - v;
}

__global__ void k_scan3(int* __restrict__ base, const int* __restrict__ chunkOff,
                        int* __restrict__ cursor) {
  int i = blockIdx.x * 256 + threadIdx.x;
  if (i < NB) {
    int b = base[i] + chunkOff[i >> 10];
    base[i] = b;
    cursor[i] = b;
  }
  if (i == 0) base[NB] = NE;
}

__global__ void k_scatter(const int* __restrict__ edst, int* __restrict__ cursor,
                          int* __restrict__ order) {
  int e = blockIdx.x * 256 + threadIdx.x;
  int key = edst[e] + ((e >= EH) ? NN : 0);
  int pos = atomicAdd(&cursor[key], 1);
  order[pos] = e;
}

// one wave per bucket: Apack[dst][seg] = sum of conj(xf[src])*rf[type]*norm (bf16 out)
__global__ __launch_bounds__(256) void k_reduce(
    const u16* __restrict__ xfh, const u16* __restrict__ rfh,
    const int* __restrict__ order, const int* __restrict__ esrc,
    const int* __restrict__ etyp, const float* __restrict__ enorm,
    const int* __restrict__ base, u16* __restrict__ Ap) {
  int w = threadIdx.x >> 6, lane = threadIdx.x & 63;
  int b = blockIdx.x * 4 + w;
  int start = base[b], end = base[b + 1];
  float a0 = 0, a1 = 0, a2 = 0, a3 = 0;
  float nyr = 0, nyi = 0;
  for (int p = start; p < end; ++p) {
    int e = order[p];
    int s = esrc[e], r = etyp[e];
    float nm = enorm[e];
    const u16* xp = xfh + (size_t)s * NFP;
    const u16* rp = rfh + (size_t)r * NFP;
    ushort4 xv = *(const ushort4*)(xp + 4 * lane);
    ushort4 rv = *(const ushort4*)(rp + 4 * lane);
    float xr0 = bu2f(xv.x), xi0 = bu2f(xv.y), xr1 = bu2f(xv.z), xi1 = bu2f(xv.w);
    float rr0 = bu2f(rv.x), ri0 = bu2f(rv.y), rr1 = bu2f(rv.z), ri1 = bu2f(rv.w);
    a0 += (xr0 * rr0 + xi0 * ri0) * nm;
    a1 += (xr0 * ri0 - xi0 * rr0) * nm;
    a2 += (xr1 * rr1 + xi1 * ri1) * nm;
    a3 += (xr1 * ri1 - xi1 * rr1) * nm;
    if (lane == 0) {
      float ar = bu2f(xp[256]), ai = bu2f(xp[257]);
      float br = bu2f(rp[256]), bi = bu2f(rp[257]);
      nyr += (ar * br + ai * bi) * nm;
      nyi += (ar * bi - ai * br) * nm;
    }
  }
  u16* tp = Ap + ((b < NN) ? (size_t)b * KP : (size_t)(b - NN) * KP + 258);
  *(unsigned int*)(tp + 4 * lane)     = pk2(a0, a1);
  *(unsigned int*)(tp + 4 * lane + 2) = pk2(a2, a3);
  if (lane == 0) *(unsigned int*)(tp + 256) = pk2(nyr, nyi);
}

// MFMA GEMM: dout[80000][256] = Apack[80000][832]bf16 x Bt^T + bias
// 128x128 tile, 4 waves x 64x64, BK=64, XOR-swizzled LDS, reg-staged prefetch
__global__ __launch_bounds__(256) void k_mgemm(
    const u16* __restrict__ Ap, const u16* __restrict__ Bt,
    const float* __restrict__ bias, float* __restrict__ dout) {
  __shared__ u16 sA[128 * 64];
  __shared__ u16 sB[128 * 64];
  int tid = threadIdx.x;
  int mt0 = (blockIdx.x >> 1) * 128;
  int nt0 = (blockIdx.x & 1) * 128;
  int w = tid >> 6, lane = tid & 63;
  int wm = (w & 1) * 64, wn = (w >> 1) * 64;
  int fr = lane & 15, fg = lane >> 4;

  // staging: thread covers rows rbase+q*32, element cols cbe..cbe+7 of the 64-wide tile
  int rbase = tid >> 3;                 // 0..31
  int cbe = (tid & 7) * 8;              // {0,8,...,56}
  int wadr = rbase * 64 + (cbe ^ ((rbase & 7) * 8));  // swizzled LDS elem offset (+q*2048)

  f32x4 acc[4][4];
#pragma unroll
  for (int i = 0; i < 4; ++i)
#pragma unroll
    for (int j = 0; j < 4; ++j) acc[i][j] = (f32x4){0.f, 0.f, 0.f, 0.f};

  bf16x8 ra[4], rb[4];
#define LOADT(kb)                                                                  \
  {                                                                                \
    _Pragma("unroll") for (int q = 0; q < 4; ++q) {                                \
      ra[q] = *(const bf16x8*)(Ap + (size_t)(mt0 + rbase + q * 32) * KP + (kb) * 64 + cbe); \
      rb[q] = *(const bf16x8*)(Bt + (size_t)(nt0 + rbase + q * 32) * KP + (kb) * 64 + cbe); \
    }                                                                              \
  }

  LOADT(0)
  for (int kb = 0; kb < 13; ++kb) {
    __syncthreads();
#pragma unroll
    for (int q = 0; q < 4; ++q) {
      *(bf16x8*)(sA + q * 2048 + wadr) = ra[q];
      *(bf16x8*)(sB + q * 2048 + wadr) = rb[q];
    }
    __syncthreads();
    if (kb + 1 < 13) LOADT(kb + 1)
#pragma unroll
    for (int ks = 0; ks < 2; ++ks) {
      bf16x8 af[4], bf_[4];
#pragma unroll
      for (int mt = 0; mt < 4; ++mt) {
        int r = wm + mt * 16 + fr;
        af[mt] = *(const bf16x8*)(sA + r * 64 + ((ks * 32 + fg * 8) ^ ((r & 7) * 8)));
      }
#pragma unroll
      for (int nt = 0; nt < 4; ++nt) {
        int r = wn + nt * 16 + fr;
        bf_[nt] = *(const bf16x8*)(sB + r * 64 + ((ks * 32 + fg * 8) ^ ((r & 7) * 8)));
      }
#pragma unroll
      for (int mt = 0; mt < 4; ++mt)
#pragma unroll
        for (int nt = 0; nt < 4; ++nt)
          acc[mt][nt] = __builtin_amdgcn_mfma_f32_16x16x32_bf16(af[mt], bf_[nt],
                                                                acc[mt][nt], 0, 0, 0);
    }
  }
#undef LOADT

#pragma unroll
  for (int mt = 0; mt < 4; ++mt)
#pragma unroll
    for (int nt = 0; nt < 4; ++nt) {
      int cg = nt0 + wn + nt * 16 + fr;
      float bv = bias[cg];
#pragma unroll
      for (int j = 0; j < 4; ++j) {
        int rg = mt0 + wm + mt * 16 + fg * 4 + j;
        dout[(size_t)rg * DD + cg] = acc[mt][nt][j] + bv;
      }
    }
}

// per-channel sum / sumsq over dout rows
__global__ __launch_bounds__(256) void k_sums(const float* __restrict__ dout,
                                              float* __restrict__ sum1,
                                              float* __restrict__ sum2) {
  int t = threadIdx.x;                 // col
  int b = blockIdx.x;                  // 320 blocks x 250 rows
  float s1 = 0.f, s2 = 0.f;
  for (int i = 0; i < 250; ++i) {
    float v = dout[(size_t)(b * 250 + i) * DD + t];
    s1 += v; s2 += v * v;
  }
  atomicAdd(&sum1[t], s1);
  atomicAdd(&sum2[t], s2);
}

__global__ void k_stats(const float* __restrict__ sum1, const float* __restrict__ sum2,
                        float* __restrict__ mean, float* __restrict__ rstd) {
  int c = threadIdx.x;
  float m = sum1[c] * (1.0f / (float)NN);
  float var = sum2[c] * (1.0f / (float)NN) - m * m;
  mean[c] = m;
  rstd[c] = rsqrtf(var + 1e-5f);
}

__global__ void k_norm(float* __restrict__ out, const float* __restrict__ mean,
                       const float* __restrict__ rstd) {
  size_t i4 = ((size_t)blockIdx.x * 256 + threadIdx.x) * 4;
  float4* p = (float4*)(out + i4);
  float4 v = *p;
  int c0 = (int)(i4 & 255);
  v.x = (v.x - mean[c0 + 0]) * rstd[c0 + 0];
  v.y = (v.y - mean[c0 + 1]) * rstd[c0 + 1];
  v.z = (v.z - mean[c0 + 2]) * rstd[c0 + 2];
  v.w = (v.w - mean[c0 + 3]) * rstd[c0 + 3];
  *p = v;
}

__global__ void k_rel(const float* __restrict__ rel, const float* __restrict__ wrel,
                      float* __restrict__ out2) {
  __shared__ float R[DD];
  int r = blockIdx.x, c = threadIdx.x;
  R[c] = rel[(size_t)r * DD + c];
  __syncthreads();
  float acc = 0.0f;
  for (int j = 0; j < DD; ++j)
    acc += R[j] * wrel[(size_t)j * DD + c];
  out2[(size_t)r * DD + c] = acc;
}

__global__ void k_fail(float* __restrict__ out, int n) {
  int i = blockIdx.x * 256 + threadIdx.x;
  if (i < n) out[i] = 1.0e6f;   // "workspace too small" marker
}

extern "C" void kernel_launch(void* const* d_in, const int* in_sizes, int n_in,
                              void* d_out, int out_size, void* d_ws, size_t ws_size,
                              hipStream_t stream) {
  (void)in_sizes; (void)n_in;
  const float* x      = (const float*)d_in[0];
  const float* rel    = (const float*)d_in[1];
  const int*   esrc   = (const int*)d_in[2];
  const int*   edst   = (const int*)d_in[3];
  const int*   etyp   = (const int*)d_in[4];
  const float* enorm  = (const float*)d_in[5];
  const float* in_w   = (const float*)d_in[6];
  const float* out_w  = (const float*)d_in[7];
  const float* loop_w = (const float*)d_in[8];
  const float* w_rel  = (const float*)d_in[9];
  const float* lr     = (const float*)d_in[10];
  const float* bias   = (const float*)d_in[11];
  float* dout = (float*)d_out;

  char* wsb = (char*)d_ws;
  size_t off = 0;
  u16* Apack = (u16*)(wsb + off); off += (size_t)NN * KP * 2;        // 133.1 MB
  u16* Bt    = (u16*)(wsb + off); off += (size_t)DD * KP * 2;        // 0.43 MB
  u16* xfh   = (u16*)(wsb + off); off += (size_t)NN * NFP * 2;       // 41.6 MB
  u16* rfh   = (u16*)(wsb + off); off += (size_t)NR * NFP * 2;       // 0.21 MB
  float* sum1  = (float*)(wsb + off); off += DD * 4;
  float* sum2  = (float*)(wsb + off); off += DD * 4;
  float* meanb = (float*)(wsb + off); off += DD * 4;
  float* rstdb = (float*)(wsb + off); off += DD * 4;
  int* cnt   = (int*)(wsb + off); off += (NB + 1) * 4;
  int* baseA = (int*)(wsb + off); off += (NB + 1) * 4;
  int* curA  = (int*)(wsb + off); off += (size_t)NB * 4;
  int* order = (int*)(wsb + off); off += (size_t)NE * 4;
  int* chT   = (int*)(wsb + off); off += 256 * 4;
  int* chO   = (int*)(wsb + off); off += 256 * 4;

  if (ws_size < off) {
    k_fail<<<(out_size + 255) / 256, 256, 0, stream>>>(dout, out_size);
    return;
  }

  hipMemsetAsync(cnt, 0, (NB + 1) * sizeof(int), stream);
  hipMemsetAsync(sum1, 0, 2 * DD * sizeof(float), stream);
  k_rfft<<<NN, 128, 0, stream>>>(x, xfh);
  k_rfft<<<NR, 128, 0, stream>>>(rel, rfh);
  k_build_m<<<516, 256, 0, stream>>>(in_w, out_w, Bt);
  k_build_q<<<256, 256, 0, stream>>>(lr, loop_w, Bt);
  k_cvt<<<625, 256, 0, stream>>>(x, Apack);
  k_hist<<<NE / 256, 256, 0, stream>>>(edst, cnt);
  k_scan1<<<NCH, 256, 0, stream>>>(cnt, baseA, chT);
  k_scan2<<<1, 256, 0, stream>>>(chT, chO);
  k_scan3<<<(NB + 255) / 256, 256, 0, stream>>>(baseA, chO, curA);
  k_scatter<<<NE / 256, 256, 0, stream>>>(edst, curA, order);
  k_reduce<<<NB / 4, 256, 0, stream>>>(xfh, rfh, order, esrc, etyp, enorm, baseA, Apack);
  k_mgemm<<<(NN / 128) * 2, 256, 0, stream>>>(Apack, Bt, bias, dout);
  k_sums<<<320, 256, 0, stream>>>(dout, sum1, sum2);
  k_stats<<<1, 256, 0, stream>>>(sum1, sum2, meanb, rstdb);
  k_norm<<<NN * DD / 4 / 256, 256, 0, stream>>>(dout, meanb, rstdb);
  k_rel<<<NR, 256, 0, stream>>>(rel, w_rel, dout + (size_t)NN * DD);
}

// Round 5
// 541.246 us; speedup vs baseline: 9.2533x; 1.9405x over previous
//
#include <hip/hip_runtime.h>

#define NN 80000     // nodes
#define NE 800000    // edges
#define EH 400000    // first half -> in_w
#define NR 400       // relations
#define DD 256       // feature dim
#define NFP 260      // freq row stride in bf16 elems (129 complex bins = 258 used)
#define KT 772       // 258 + 258 + 256 logical GEMM K
#define KP 832       // K padded to 13*64
#define NB 160000    // sort buckets: dir*NN + dst
#define NCH 157      // ceil(NB/1024) scan chunks
#define MT 80400     // total DFT rows (x + rel)
#define PI2 6.283185307179586f

typedef unsigned short u16;
typedef __attribute__((ext_vector_type(8))) short bf16x8;
typedef __attribute__((ext_vector_type(4))) float f32x4;

static __device__ __forceinline__ float bu2f(u16 u) {
  return __uint_as_float(((unsigned int)u) << 16);
}
static __device__ __forceinline__ u16 f2bu(float f) {
  unsigned int x = __float_as_uint(f);
  x += 0x7fffu + ((x >> 16) & 1u);   // RNE
  return (u16)(x >> 16);
}
static __device__ __forceinline__ unsigned int pk2(float a, float b) {
  return (unsigned int)f2bu(a) | ((unsigned int)f2bu(b) << 16);
}

// DFT coefficient matrix: Ft[c][j]; c=2k -> cos(2pi jk/256), c=2k+1 -> -sin(2pi jk/256)
__global__ void k_build_f(u16* __restrict__ Ft) {
  int c = blockIdx.x, j = threadIdx.x;
  int k = c >> 1;
  int m = (j * k) & 255;               // angle periodic mod 256 -> exact reduction
  float th = -PI2 * (float)m * (1.0f / 256.0f);
  float v = (c & 1) ? sinf(th) : cosf(th);
  Ft[c * 256 + j] = f2bu(v);
}

// Bt rows: Bt[c][t] = (a_k/768)*[cos|-sin](2*pi*j*k/256) dot W[j][c], t=0..515
__global__ void k_build_m(const float* __restrict__ in_w, const float* __restrict__ out_w,
                          u16* __restrict__ Bt) {
  int t = blockIdx.x;                  // 0..515
  int c = threadIdx.x;                 // 0..255
  const float* W = (t < 258) ? in_w : out_w;
  int tp = (t < 258) ? t : t - 258;
  int k = tp >> 1, im = tp & 1;
  float a = (k == 0 || k == 128) ? 1.0f : 2.0f;
  float scale = a * (1.0f / (256.0f * 3.0f));
  float th = -PI2 * (float)k * (1.0f / 256.0f);
  float wr = cosf(th), wi = sinf(th);
  float zr = 1.0f, zi = 0.0f;
  float acc = 0.0f;
  for (int j = 0; j < DD; ++j) {
    float coef = im ? zi : zr;
    acc += coef * W[(size_t)j * DD + c];
    float nzr = zr * wr - zi * wi; zi = zr * wi + zi * wr; zr = nzr;
  }
  Bt[(size_t)c * KP + t] = f2bu(scale * acc);
}

// Bt[c][516+j] = (1/3) sum_k lr[(j+k)%256] * loop_w[k][c]; also zero K-pad
__global__ void k_build_q(const float* __restrict__ lr, const float* __restrict__ loop_w,
                          u16* __restrict__ Bt) {
  __shared__ float L[DD];
  int j = blockIdx.x, c = threadIdx.x;
  L[c] = lr[c];
  __syncthreads();
  float acc = 0.0f;
  for (int k2 = 0; k2 < DD; ++k2)
    acc += L[(j + k2) & 255] * loop_w[(size_t)k2 * DD + c];
  Bt[(size_t)c * KP + 516 + j] = f2bu(acc * (1.0f / 3.0f));
  if (j < KP - KT) Bt[(size_t)c * KP + KT + j] = 0;
}

// x -> bf16 into Apack cols 516..771 (zero 772..831) AND contiguous xb rows 0..NN-1
__global__ void k_cvt(const float* __restrict__ x, u16* __restrict__ Ap,
                      u16* __restrict__ xb) {
  int t = threadIdx.x, b = blockIdx.x;  // 625 blocks x 128 rows
  for (int i = 0; i < 128; ++i) {
    size_t r = (size_t)b * 128 + i;
    u16 v = f2bu(x[r * DD + t]);
    Ap[r * KP + 516 + t] = v;
    xb[r * DD + t] = v;
    if (t < KP - KT) Ap[r * KP + KT + t] = 0;
  }
}

// rel -> bf16 into xb rows NN..NN+399
__global__ void k_cvtr(const float* __restrict__ rel, u16* __restrict__ xb) {
  int t = threadIdx.x, r = blockIdx.x;
  xb[(size_t)(NN + r) * DD + t] = f2bu(rel[(size_t)r * DD + t]);
}

// Nyquist bin: xf[row][256] = sum_j xb_j*(-1)^j ; [257] = 0. One wave per row.
__global__ __launch_bounds__(256) void k_nyq(const float* __restrict__ x,
                                             const float* __restrict__ rel,
                                             u16* __restrict__ xfh, u16* __restrict__ rfh) {
  int w = threadIdx.x >> 6, lane = threadIdx.x & 63;
  int row = blockIdx.x * 4 + w;
  if (row >= MT) return;
  const float* src = (row < NN) ? (x + (size_t)row * DD) : (rel + (size_t)(row - NN) * DD);
  float4 v = *(const float4*)(src + 4 * lane);
  float s = v.x - v.y + v.z - v.w;
#pragma unroll
  for (int off = 32; off > 0; off >>= 1) s += __shfl_xor(s, off);
  if (lane == 0) {
    u16* dst = (row < NN) ? (xfh + (size_t)row * NFP) : (rfh + (size_t)(row - NN) * NFP);
    dst[256] = f2bu(s);
    dst[257] = 0;
  }
}

// MFMA DFT: XF[MT][256] = xb[MT][256] @ Ft^T, bf16 out to xfh/rfh (stride NFP)
__global__ __launch_bounds__(256) void k_dft(
    const u16* __restrict__ xb, const u16* __restrict__ Ft,
    u16* __restrict__ xfh, u16* __restrict__ rfh) {
  __shared__ u16 sA[128 * 64];
  __shared__ u16 sB[128 * 64];
  int tid = threadIdx.x;
  int mt0 = (int)(blockIdx.x >> 1) * 128;
  int nt0 = (blockIdx.x & 1) * 128;
  int w = tid >> 6, lane = tid & 63;
  int wm = (w & 1) * 64, wn = (w >> 1) * 64;
  int fr = lane & 15, fg = lane >> 4;
  int rbase = tid >> 3;
  int cbe = (tid & 7) * 8;
  int wadr = rbase * 64 + (cbe ^ ((rbase & 7) * 8));

  f32x4 acc[4][4];
#pragma unroll
  for (int i = 0; i < 4; ++i)
#pragma unroll
    for (int j = 0; j < 4; ++j) acc[i][j] = (f32x4){0.f, 0.f, 0.f, 0.f};

  bf16x8 ra[4], rb[4];
#define LOADT(kb)                                                                   \
  {                                                                                 \
    _Pragma("unroll") for (int q = 0; q < 4; ++q) {                                 \
      int rr = mt0 + rbase + q * 32; if (rr > MT - 1) rr = MT - 1;                  \
      ra[q] = *(const bf16x8*)(xb + (size_t)rr * DD + (kb) * 64 + cbe);             \
      rb[q] = *(const bf16x8*)(Ft + (size_t)(nt0 + rbase + q * 32) * DD + (kb) * 64 + cbe); \
    }                                                                               \
  }

  LOADT(0)
  for (int kb = 0; kb < 4; ++kb) {
    __syncthreads();
#pragma unroll
    for (int q = 0; q < 4; ++q) {
      *(bf16x8*)(sA + q * 2048 + wadr) = ra[q];
      *(bf16x8*)(sB + q * 2048 + wadr) = rb[q];
    }
    __syncthreads();
    if (kb + 1 < 4) LOADT(kb + 1)
#pragma unroll
    for (int ks = 0; ks < 2; ++ks) {
      bf16x8 af[4], bf_[4];
#pragma unroll
      for (int mt = 0; mt < 4; ++mt) {
        int r = wm + mt * 16 + fr;
        af[mt] = *(const bf16x8*)(sA + r * 64 + ((ks * 32 + fg * 8) ^ ((r & 7) * 8)));
      }
#pragma unroll
      for (int nt = 0; nt < 4; ++nt) {
        int r = wn + nt * 16 + fr;
        bf_[nt] = *(const bf16x8*)(sB + r * 64 + ((ks * 32 + fg * 8) ^ ((r & 7) * 8)));
      }
#pragma unroll
      for (int mt = 0; mt < 4; ++mt)
#pragma unroll
        for (int nt = 0; nt < 4; ++nt)
          acc[mt][nt] = __builtin_amdgcn_mfma_f32_16x16x32_bf16(af[mt], bf_[nt],
                                                                acc[mt][nt], 0, 0, 0);
    }
  }
#undef LOADT

#pragma unroll
  for (int mt = 0; mt < 4; ++mt)
#pragma unroll
    for (int nt = 0; nt < 4; ++nt) {
      int cg = nt0 + wn + nt * 16 + fr;
#pragma unroll
      for (int j = 0; j < 4; ++j) {
        int rg = mt0 + wm + mt * 16 + fg * 4 + j;
        u16 val = f2bu(acc[mt][nt][j]);
        if (rg < NN)      xfh[(size_t)rg * NFP + cg] = val;
        else if (rg < MT) rfh[(size_t)(rg - NN) * NFP + cg] = val;
      }
    }
}

// ---------- counting sort by key = (e>=EH)*NN + dst ----------
__global__ void k_hist(const int* __restrict__ edst, int* __restrict__ cnt) {
  int e = blockIdx.x * 256 + threadIdx.x;
  int key = edst[e] + ((e >= EH) ? NN : 0);
  atomicAdd(&cnt[key], 1);
}

__global__ __launch_bounds__(256) void k_scan1(const int* __restrict__ cnt,
                                               int* __restrict__ base,
                                               int* __restrict__ chunkTot) {
  __shared__ int wsum[4];
  int t = threadIdx.x;
  int g0 = blockIdx.x * 1024 + t * 4;
  int v[4], ex[4], s = 0;
#pragma unroll
  for (int j = 0; j < 4; ++j) v[j] = (g0 + j < NB) ? cnt[g0 + j] : 0;
#pragma unroll
  for (int j = 0; j < 4; ++j) { ex[j] = s; s += v[j]; }
  int lane = t & 63, w = t >> 6;
  int inc = s;
  for (int off = 1; off < 64; off <<= 1) {
    int n = __shfl_up(inc, off);
    if (lane >= off) inc += n;
  }
  if (lane == 63) wsum[w] = inc;
  __syncthreads();
  int woff = 0;
  for (int i = 0; i < w; ++i) woff += wsum[i];
  int exth = woff + inc - s;
#pragma unroll
  for (int j = 0; j < 4; ++j)
    if (g0 + j < NB) base[g0 + j] = exth + ex[j];
  if (t == 255) chunkTot[blockIdx.x] = woff + inc;
}

__global__ __launch_bounds__(256) void k_scan2(const int* __restrict__ chunkTot,
                                               int* __restrict__ chunkOff) {
  __shared__ int wsum[4];
  int t = threadIdx.x;
  int v = (t < NCH) ? chunkTot[t] : 0;
  int lane = t & 63, w = t >> 6;
  int inc = v;
  for (int off = 1; off < 64; off <<= 1) {
    int n = __shfl_up(inc, off);
    if (lane >= off) inc += n;
  }
  if (lane == 63) wsum[w] = inc;
  __syncthreads();
  int woff = 0;
  for (int i = 0; i < w; ++i) woff += wsum[i];
  if (t < NCH) chunkOff[t] = woff + inc - v;
}

__global__ void k_scan3(int* __restrict__ base, const int* __restrict__ chunkOff,
                        int* __restrict__ cursor) {
  int i = blockIdx.x * 256 + threadIdx.x;
  if (i < NB) {
    int b = base[i] + chunkOff[i >> 10];
    base[i] = b;
    cursor[i] = b;
  }
  if (i == 0) base[NB] = NE;
}

__global__ void k_scatter(const int* __restrict__ edst, int* __restrict__ cursor,
                          int* __restrict__ order) {
  int e = blockIdx.x * 256 + threadIdx.x;
  int key = edst[e] + ((e >= EH) ? NN : 0);
  int pos = atomicAdd(&cursor[key], 1);
  order[pos] = e;
}

// one wave per bucket: Apack[dst][seg] = sum of conj(xf[src])*rf[type]*norm (bf16 out)
__global__ __launch_bounds__(256) void k_reduce(
    const u16* __restrict__ xfh, const u16* __restrict__ rfh,
    const int* __restrict__ order, const int* __restrict__ esrc,
    const int* __restrict__ etyp, const float* __restrict__ enorm,
    const int* __restrict__ base, u16* __restrict__ Ap) {
  int w = threadIdx.x >> 6, lane = threadIdx.x & 63;
  int b = blockIdx.x * 4 + w;
  int start = base[b], end = base[b + 1];
  float a0 = 0, a1 = 0, a2 = 0, a3 = 0;
  float nyr = 0, nyi = 0;
  for (int p = start; p < end; ++p) {
    int e = order[p];
    int s = esrc[e], r = etyp[e];
    float nm = enorm[e];
    const u16* xp = xfh + (size_t)s * NFP;
    const u16* rp = rfh + (size_t)r * NFP;
    ushort4 xv = *(const ushort4*)(xp + 4 * lane);
    ushort4 rv = *(const ushort4*)(rp + 4 * lane);
    float xr0 = bu2f(xv.x), xi0 = bu2f(xv.y), xr1 = bu2f(xv.z), xi1 = bu2f(xv.w);
    float rr0 = bu2f(rv.x), ri0 = bu2f(rv.y), rr1 = bu2f(rv.z), ri1 = bu2f(rv.w);
    a0 += (xr0 * rr0 + xi0 * ri0) * nm;
    a1 += (xr0 * ri0 - xi0 * rr0) * nm;
    a2 += (xr1 * rr1 + xi1 * ri1) * nm;
    a3 += (xr1 * ri1 - xi1 * rr1) * nm;
    if (lane == 0) {
      float ar = bu2f(xp[256]), ai = bu2f(xp[257]);
      float br = bu2f(rp[256]), bi = bu2f(rp[257]);
      nyr += (ar * br + ai * bi) * nm;
      nyi += (ar * bi - ai * br) * nm;
    }
  }
  u16* tp = Ap + ((b < NN) ? (size_t)b * KP : (size_t)(b - NN) * KP + 258);
  *(unsigned int*)(tp + 4 * lane)     = pk2(a0, a1);
  *(unsigned int*)(tp + 4 * lane + 2) = pk2(a2, a3);
  if (lane == 0) *(unsigned int*)(tp + 256) = pk2(nyr, nyi);
}

// MFMA GEMM: dout[80000][256] = Apack[80000][832]bf16 x Bt^T + bias
__global__ __launch_bounds__(256) void k_mgemm(
    const u16* __restrict__ Ap, const u16* __restrict__ Bt,
    const float* __restrict__ bias, float* __restrict__ dout) {
  __shared__ u16 sA[128 * 64];
  __shared__ u16 sB[128 * 64];
  int tid = threadIdx.x;
  int mt0 = (blockIdx.x >> 1) * 128;
  int nt0 = (blockIdx.x & 1) * 128;
  int w = tid >> 6, lane = tid & 63;
  int wm = (w & 1) * 64, wn = (w >> 1) * 64;
  int fr = lane & 15, fg = lane >> 4;
  int rbase = tid >> 3;
  int cbe = (tid & 7) * 8;
  int wadr = rbase * 64 + (cbe ^ ((rbase & 7) * 8));

  f32x4 acc[4][4];
#pragma unroll
  for (int i = 0; i < 4; ++i)
#pragma unroll
    for (int j = 0; j < 4; ++j) acc[i][j] = (f32x4){0.f, 0.f, 0.f, 0.f};

  bf16x8 ra[4], rb[4];
#define LOADT(kb)                                                                  \
  {                                                                                \
    _Pragma("unroll") for (int q = 0; q < 4; ++q) {                                \
      ra[q] = *(const bf16x8*)(Ap + (size_t)(mt0 + rbase + q * 32) * KP + (kb) * 64 + cbe); \
      rb[q] = *(const bf16x8*)(Bt + (size_t)(nt0 + rbase + q * 32) * KP + (kb) * 64 + cbe); \
    }                                                                              \
  }

  LOADT(0)
  for (int kb = 0; kb < 13; ++kb) {
    __syncthreads();
#pragma unroll
    for (int q = 0; q < 4; ++q) {
      *(bf16x8*)(sA + q * 2048 + wadr) = ra[q];
      *(bf16x8*)(sB + q * 2048 + wadr) = rb[q];
    }
    __syncthreads();
    if (kb + 1 < 13) LOADT(kb + 1)
#pragma unroll
    for (int ks = 0; ks < 2; ++ks) {
      bf16x8 af[4], bf_[4];
#pragma unroll
      for (int mt = 0; mt < 4; ++mt) {
        int r = wm + mt * 16 + fr;
        af[mt] = *(const bf16x8*)(sA + r * 64 + ((ks * 32 + fg * 8) ^ ((r & 7) * 8)));
      }
#pragma unroll
      for (int nt = 0; nt < 4; ++nt) {
        int r = wn + nt * 16 + fr;
        bf_[nt] = *(const bf16x8*)(sB + r * 64 + ((ks * 32 + fg * 8) ^ ((r & 7) * 8)));
      }
#pragma unroll
      for (int mt = 0; mt < 4; ++mt)
#pragma unroll
        for (int nt = 0; nt < 4; ++nt)
          acc[mt][nt] = __builtin_amdgcn_mfma_f32_16x16x32_bf16(af[mt], bf_[nt],
                                                                acc[mt][nt], 0, 0, 0);
    }
  }
#undef LOADT

#pragma unroll
  for (int mt = 0; mt < 4; ++mt)
#pragma unroll
    for (int nt = 0; nt < 4; ++nt) {
      int cg = nt0 + wn + nt * 16 + fr;
      float bv = bias[cg];
#pragma unroll
      for (int j = 0; j < 4; ++j) {
        int rg = mt0 + wm + mt * 16 + fg * 4 + j;
        dout[(size_t)rg * DD + cg] = acc[mt][nt][j] + bv;
      }
    }
}

// per-channel sum / sumsq over dout rows
__global__ __launch_bounds__(256) void k_sums(const float* __restrict__ dout,
                                              float* __restrict__ sum1,
                                              float* __restrict__ sum2) {
  int t = threadIdx.x;
  int b = blockIdx.x;
  float s1 = 0.f, s2 = 0.f;
  for (int i = 0; i < 250; ++i) {
    float v = dout[(size_t)(b * 250 + i) * DD + t];
    s1 += v; s2 += v * v;
  }
  atomicAdd(&sum1[t], s1);
  atomicAdd(&sum2[t], s2);
}

__global__ void k_stats(const float* __restrict__ sum1, const float* __restrict__ sum2,
                        float* __restrict__ mean, float* __restrict__ rstd) {
  int c = threadIdx.x;
  float m = sum1[c] * (1.0f / (float)NN);
  float var = sum2[c] * (1.0f / (float)NN) - m * m;
  mean[c] = m;
  rstd[c] = rsqrtf(var + 1e-5f);
}

__global__ void k_norm(float* __restrict__ out, const float* __restrict__ mean,
                       const float* __restrict__ rstd) {
  size_t i4 = ((size_t)blockIdx.x * 256 + threadIdx.x) * 4;
  float4* p = (float4*)(out + i4);
  float4 v = *p;
  int c0 = (int)(i4 & 255);
  v.x = (v.x - mean[c0 + 0]) * rstd[c0 + 0];
  v.y = (v.y - mean[c0 + 1]) * rstd[c0 + 1];
  v.z = (v.z - mean[c0 + 2]) * rstd[c0 + 2];
  v.w = (v.w - mean[c0 + 3]) * rstd[c0 + 3];
  *p = v;
}

__global__ void k_rel(const float* __restrict__ rel, const float* __restrict__ wrel,
                      float* __restrict__ out2) {
  __shared__ float R[DD];
  int r = blockIdx.x, c = threadIdx.x;
  R[c] = rel[(size_t)r * DD + c];
  __syncthreads();
  float acc = 0.0f;
  for (int j = 0; j < DD; ++j)
    acc += R[j] * wrel[(size_t)j * DD + c];
  out2[(size_t)r * DD + c] = acc;
}

__global__ void k_fail(float* __restrict__ out, int n) {
  int i = blockIdx.x * 256 + threadIdx.x;
  if (i < n) out[i] = 1.0e6f;   // "workspace too small" marker
}

extern "C" void kernel_launch(void* const* d_in, const int* in_sizes, int n_in,
                              void* d_out, int out_size, void* d_ws, size_t ws_size,
                              hipStream_t stream) {
  (void)in_sizes; (void)n_in;
  const float* x      = (const float*)d_in[0];
  const float* rel    = (const float*)d_in[1];
  const int*   esrc   = (const int*)d_in[2];
  const int*   edst   = (const int*)d_in[3];
  const int*   etyp   = (const int*)d_in[4];
  const float* enorm  = (const float*)d_in[5];
  const float* in_w   = (const float*)d_in[6];
  const float* out_w  = (const float*)d_in[7];
  const float* loop_w = (const float*)d_in[8];
  const float* w_rel  = (const float*)d_in[9];
  const float* lr     = (const float*)d_in[10];
  const float* bias   = (const float*)d_in[11];
  float* dout = (float*)d_out;

  char* wsb = (char*)d_ws;
  size_t off = 0;
  u16* Apack = (u16*)(wsb + off); off += (size_t)NN * KP * 2;        // 133.1 MB
  u16* Bt    = (u16*)(wsb + off); off += (size_t)DD * KP * 2;        // 0.43 MB
  u16* xfh   = (u16*)(wsb + off); off += (size_t)NN * NFP * 2;       // 41.6 MB
  u16* rfh   = (u16*)(wsb + off); off += (size_t)NR * NFP * 2;       // 0.21 MB
  u16* xb    = (u16*)(wsb + off); off += (size_t)MT * DD * 2;        // 41.2 MB
  u16* Ft    = (u16*)(wsb + off); off += (size_t)DD * DD * 2;        // 0.13 MB
  float* sum1  = (float*)(wsb + off); off += DD * 4;
  float* sum2  = (float*)(wsb + off); off += DD * 4;
  float* meanb = (float*)(wsb + off); off += DD * 4;
  float* rstdb = (float*)(wsb + off); off += DD * 4;
  int* cnt   = (int*)(wsb + off); off += (NB + 1) * 4;
  int* baseA = (int*)(wsb + off); off += (NB + 1) * 4;
  int* curA  = (int*)(wsb + off); off += (size_t)NB * 4;
  int* order = (int*)(wsb + off); off += (size_t)NE * 4;
  int* chT   = (int*)(wsb + off); off += 256 * 4;
  int* chO   = (int*)(wsb + off); off += 256 * 4;

  if (ws_size < off) {
    k_fail<<<(out_size + 255) / 256, 256, 0, stream>>>(dout, out_size);
    return;
  }

  hipMemsetAsync(cnt, 0, (NB + 1) * sizeof(int), stream);
  hipMemsetAsync(sum1, 0, 2 * DD * sizeof(float), stream);
  k_cvt<<<625, 256, 0, stream>>>(x, Apack, xb);
  k_cvtr<<<NR, 256, 0, stream>>>(rel, xb);
  k_build_f<<<256, 256, 0, stream>>>(Ft);
  k_build_m<<<516, 256, 0, stream>>>(in_w, out_w, Bt);
  k_build_q<<<256, 256, 0, stream>>>(lr, loop_w, Bt);
  k_dft<<<629 * 2, 256, 0, stream>>>(xb, Ft, xfh, rfh);
  k_nyq<<<(MT + 3) / 4, 256, 0, stream>>>(x, rel, xfh, rfh);
  k_hist<<<NE / 256, 256, 0, stream>>>(edst, cnt);
  k_scan1<<<NCH, 256, 0, stream>>>(cnt, baseA, chT);
  k_scan2<<<1, 256, 0, stream>>>(chT, chO);
  k_scan3<<<(NB + 255) / 256, 256, 0, stream>>>(baseA, chO, curA);
  k_scatter<<<NE / 256, 256, 0, stream>>>(edst, curA, order);
  k_reduce<<<NB / 4, 256, 0, stream>>>(xfh, rfh, order, esrc, etyp, enorm, baseA, Apack);
  k_mgemm<<<(NN / 128) * 2, 256, 0, stream>>>(Apack, Bt, bias, dout);
  k_sums<<<320, 256, 0, stream>>>(dout, sum1, sum2);
  k_stats<<<1, 256, 0, stream>>>(sum1, sum2, meanb, rstdb);
  k_norm<<<NN * DD / 4 / 256, 256, 0, stream>>>(dout, meanb, rstdb);
  k_rel<<<NR, 256, 0, stream>>>(rel, w_rel, dout + (size_t)NN * DD);
}

// Round 6
// 512.560 us; speedup vs baseline: 9.7711x; 1.0560x over previous
//
#include <hip/hip_runtime.h>

#define NN 80000     // nodes
#define NE 800000    // edges
#define EH 400000    // first half -> in_w
#define NR 400       // relations
#define DD 256       // feature dim
#define NFP 260      // freq row stride in bf16 elems (129 complex bins = 258 used)
#define KT 772       // 258 + 258 + 256 logical GEMM K
#define KP 832       // K padded to 13*64
#define NB 160000    // sort buckets: dir*NN + dst
#define NCH 157      // ceil(NB/1024) scan chunks
#define MT 80400     // total DFT rows (x + rel)
#define PI2 6.283185307179586f

typedef unsigned short u16;
typedef __attribute__((ext_vector_type(8))) short bf16x8;
typedef __attribute__((ext_vector_type(4))) float f32x4;

static __device__ __forceinline__ float bu2f(u16 u) {
  return __uint_as_float(((unsigned int)u) << 16);
}
static __device__ __forceinline__ u16 f2bu(float f) {
  unsigned int x = __float_as_uint(f);
  x += 0x7fffu + ((x >> 16) & 1u);   // RNE
  return (u16)(x >> 16);
}
static __device__ __forceinline__ unsigned int pk2(float a, float b) {
  return (unsigned int)f2bu(a) | ((unsigned int)f2bu(b) << 16);
}
// async global->LDS 16B: lds dest = wave-uniform base + lane*16
static __device__ __forceinline__ void gload16(const void* g, void* l) {
  __builtin_amdgcn_global_load_lds(
      (const __attribute__((address_space(1))) unsigned int*)g,
      (__attribute__((address_space(3))) unsigned int*)l, 16, 0, 0);
}

// DFT coefficient matrix: Ft[c][j]; c=2k -> cos(2pi jk/256), c=2k+1 -> -sin(2pi jk/256)
__global__ void k_build_f(u16* __restrict__ Ft) {
  int c = blockIdx.x, j = threadIdx.x;
  int k = c >> 1;
  int m = (j * k) & 255;               // exact mod-256 angle reduction
  float th = -PI2 * (float)m * (1.0f / 256.0f);
  float v = (c & 1) ? sinf(th) : cosf(th);
  Ft[c * 256 + j] = f2bu(v);
}

// Bt rows: Bt[c][t] = (a_k/768)*[cos|-sin](2*pi*j*k/256) dot W[j][c], t=0..515
__global__ void k_build_m(const float* __restrict__ in_w, const float* __restrict__ out_w,
                          u16* __restrict__ Bt) {
  int t = blockIdx.x;                  // 0..515
  int c = threadIdx.x;                 // 0..255
  const float* W = (t < 258) ? in_w : out_w;
  int tp = (t < 258) ? t : t - 258;
  int k = tp >> 1, im = tp & 1;
  float a = (k == 0 || k == 128) ? 1.0f : 2.0f;
  float scale = a * (1.0f / (256.0f * 3.0f));
  float th = -PI2 * (float)k * (1.0f / 256.0f);
  float wr = cosf(th), wi = sinf(th);
  float zr = 1.0f, zi = 0.0f;
  float acc = 0.0f;
  for (int j = 0; j < DD; ++j) {
    float coef = im ? zi : zr;
    acc += coef * W[(size_t)j * DD + c];
    float nzr = zr * wr - zi * wi; zi = zr * wi + zi * wr; zr = nzr;
  }
  Bt[(size_t)c * KP + t] = f2bu(scale * acc);
}

// Bt[c][516+j] = (1/3) sum_k lr[(j+k)%256] * loop_w[k][c]; also zero K-pad
__global__ void k_build_q(const float* __restrict__ lr, const float* __restrict__ loop_w,
                          u16* __restrict__ Bt) {
  __shared__ float L[DD];
  int j = blockIdx.x, c = threadIdx.x;
  L[c] = lr[c];
  __syncthreads();
  float acc = 0.0f;
  for (int k2 = 0; k2 < DD; ++k2)
    acc += L[(j + k2) & 255] * loop_w[(size_t)k2 * DD + c];
  Bt[(size_t)c * KP + 516 + j] = f2bu(acc * (1.0f / 3.0f));
  if (j < KP - KT) Bt[(size_t)c * KP + KT + j] = 0;
}

// x -> bf16 into Apack cols 516..771 (zero 772..831) AND contiguous xb rows 0..NN-1
__global__ void k_cvt(const float* __restrict__ x, u16* __restrict__ Ap,
                      u16* __restrict__ xb) {
  int t = threadIdx.x, b = blockIdx.x;  // 625 blocks x 128 rows
  for (int i = 0; i < 128; ++i) {
    size_t r = (size_t)b * 128 + i;
    u16 v = f2bu(x[r * DD + t]);
    Ap[r * KP + 516 + t] = v;
    xb[r * DD + t] = v;
    if (t < KP - KT) Ap[r * KP + KT + t] = 0;
  }
}

// rel -> bf16 into xb rows NN..NN+399
__global__ void k_cvtr(const float* __restrict__ rel, u16* __restrict__ xb) {
  int t = threadIdx.x, r = blockIdx.x;
  xb[(size_t)(NN + r) * DD + t] = f2bu(rel[(size_t)r * DD + t]);
}

// Nyquist bin: xf[row][256] = sum_j xb_j*(-1)^j ; [257] = 0. One wave per row.
__global__ __launch_bounds__(256) void k_nyq(const float* __restrict__ x,
                                             const float* __restrict__ rel,
                                             u16* __restrict__ xfh, u16* __restrict__ rfh) {
  int w = threadIdx.x >> 6, lane = threadIdx.x & 63;
  int row = blockIdx.x * 4 + w;
  if (row >= MT) return;
  const float* src = (row < NN) ? (x + (size_t)row * DD) : (rel + (size_t)(row - NN) * DD);
  float4 v = *(const float4*)(src + 4 * lane);
  float s = v.x - v.y + v.z - v.w;
#pragma unroll
  for (int off = 32; off > 0; off >>= 1) s += __shfl_xor(s, off);
  if (lane == 0) {
    u16* dst = (row < NN) ? (xfh + (size_t)row * NFP) : (rfh + (size_t)(row - NN) * NFP);
    dst[256] = f2bu(s);
    dst[257] = 0;
  }
}

// MFMA DFT: XF[MT][256] = xb[MT][256] @ Ft^T, bf16 out to xfh/rfh (stride NFP)
__global__ __launch_bounds__(256) void k_dft(
    const u16* __restrict__ xb, const u16* __restrict__ Ft,
    u16* __restrict__ xfh, u16* __restrict__ rfh) {
  __shared__ u16 sA[128 * 64];
  __shared__ u16 sB[128 * 64];
  int tid = threadIdx.x;
  int mt0 = (int)(blockIdx.x >> 1) * 128;
  int nt0 = (blockIdx.x & 1) * 128;
  int w = tid >> 6, lane = tid & 63;
  int wm = (w & 1) * 64, wn = (w >> 1) * 64;
  int fr = lane & 15, fg = lane >> 4;
  int rbase = tid >> 3;
  int cbe = (tid & 7) * 8;
  int wadr = rbase * 64 + (cbe ^ ((rbase & 7) * 8));

  f32x4 acc[4][4];
#pragma unroll
  for (int i = 0; i < 4; ++i)
#pragma unroll
    for (int j = 0; j < 4; ++j) acc[i][j] = (f32x4){0.f, 0.f, 0.f, 0.f};

  bf16x8 ra[4], rb[4];
#define LOADT(kb)                                                                   \
  {                                                                                 \
    _Pragma("unroll") for (int q = 0; q < 4; ++q) {                                 \
      int rr = mt0 + rbase + q * 32; if (rr > MT - 1) rr = MT - 1;                  \
      ra[q] = *(const bf16x8*)(xb + (size_t)rr * DD + (kb) * 64 + cbe);             \
      rb[q] = *(const bf16x8*)(Ft + (size_t)(nt0 + rbase + q * 32) * DD + (kb) * 64 + cbe); \
    }                                                                               \
  }

  LOADT(0)
  for (int kb = 0; kb < 4; ++kb) {
    __syncthreads();
#pragma unroll
    for (int q = 0; q < 4; ++q) {
      *(bf16x8*)(sA + q * 2048 + wadr) = ra[q];
      *(bf16x8*)(sB + q * 2048 + wadr) = rb[q];
    }
    __syncthreads();
    if (kb + 1 < 4) LOADT(kb + 1)
#pragma unroll
    for (int ks = 0; ks < 2; ++ks) {
      bf16x8 af[4], bf_[4];
#pragma unroll
      for (int mt = 0; mt < 4; ++mt) {
        int r = wm + mt * 16 + fr;
        af[mt] = *(const bf16x8*)(sA + r * 64 + ((ks * 32 + fg * 8) ^ ((r & 7) * 8)));
      }
#pragma unroll
      for (int nt = 0; nt < 4; ++nt) {
        int r = wn + nt * 16 + fr;
        bf_[nt] = *(const bf16x8*)(sB + r * 64 + ((ks * 32 + fg * 8) ^ ((r & 7) * 8)));
      }
#pragma unroll
      for (int mt = 0; mt < 4; ++mt)
#pragma unroll
        for (int nt = 0; nt < 4; ++nt)
          acc[mt][nt] = __builtin_amdgcn_mfma_f32_16x16x32_bf16(af[mt], bf_[nt],
                                                                acc[mt][nt], 0, 0, 0);
    }
  }
#undef LOADT

#pragma unroll
  for (int mt = 0; mt < 4; ++mt)
#pragma unroll
    for (int nt = 0; nt < 4; ++nt) {
      int cg = nt0 + wn + nt * 16 + fr;
#pragma unroll
      for (int j = 0; j < 4; ++j) {
        int rg = mt0 + wm + mt * 16 + fg * 4 + j;
        u16 val = f2bu(acc[mt][nt][j]);
        if (rg < NN)      xfh[(size_t)rg * NFP + cg] = val;
        else if (rg < MT) rfh[(size_t)(rg - NN) * NFP + cg] = val;
      }
    }
}

// ---------- counting sort by key = (e>=EH)*NN + dst ----------
__global__ void k_hist(const int* __restrict__ edst, int* __restrict__ cnt) {
  int e = blockIdx.x * 256 + threadIdx.x;
  int key = edst[e] + ((e >= EH) ? NN : 0);
  atomicAdd(&cnt[key], 1);
}

__global__ __launch_bounds__(256) void k_scan1(const int* __restrict__ cnt,
                                               int* __restrict__ base,
                                               int* __restrict__ chunkTot) {
  __shared__ int wsum[4];
  int t = threadIdx.x;
  int g0 = blockIdx.x * 1024 + t * 4;
  int v[4], ex[4], s = 0;
#pragma unroll
  for (int j = 0; j < 4; ++j) v[j] = (g0 + j < NB) ? cnt[g0 + j] : 0;
#pragma unroll
  for (int j = 0; j < 4; ++j) { ex[j] = s; s += v[j]; }
  int lane = t & 63, w = t >> 6;
  int inc = s;
  for (int off = 1; off < 64; off <<= 1) {
    int n = __shfl_up(inc, off);
    if (lane >= off) inc += n;
  }
  if (lane == 63) wsum[w] = inc;
  __syncthreads();
  int woff = 0;
  for (int i = 0; i < w; ++i) woff += wsum[i];
  int exth = woff + inc - s;
#pragma unroll
  for (int j = 0; j < 4; ++j)
    if (g0 + j < NB) base[g0 + j] = exth + ex[j];
  if (t == 255) chunkTot[blockIdx.x] = woff + inc;
}

__global__ __launch_bounds__(256) void k_scan2(const int* __restrict__ chunkTot,
                                               int* __restrict__ chunkOff) {
  __shared__ int wsum[4];
  int t = threadIdx.x;
  int v = (t < NCH) ? chunkTot[t] : 0;
  int lane = t & 63, w = t >> 6;
  int inc = v;
  for (int off = 1; off < 64; off <<= 1) {
    int n = __shfl_up(inc, off);
    if (lane >= off) inc += n;
  }
  if (lane == 63) wsum[w] = inc;
  __syncthreads();
  int woff = 0;
  for (int i = 0; i < w; ++i) woff += wsum[i];
  if (t < NCH) chunkOff[t] = woff + inc - v;
}

__global__ void k_scan3(int* __restrict__ base, const int* __restrict__ chunkOff,
                        int* __restrict__ cursor) {
  int i = blockIdx.x * 256 + threadIdx.x;
  if (i < NB) {
    int b = base[i] + chunkOff[i >> 10];
    base[i] = b;
    cursor[i] = b;
  }
  if (i == 0) base[NB] = NE;
}

// scatter packed records: (src, typ, norm_bits, 0) -> sorted position
__global__ void k_scatter(const int* __restrict__ esrc, const int* __restrict__ edst,
                          const int* __restrict__ etyp, const float* __restrict__ enorm,
                          int* __restrict__ cursor, int4* __restrict__ recs) {
  int e = blockIdx.x * 256 + threadIdx.x;
  int key = edst[e] + ((e >= EH) ? NN : 0);
  int pos = atomicAdd(&cursor[key], 1);
  recs[pos] = make_int4(esrc[e], etyp[e], __float_as_int(enorm[e]), 0);
}

// one wave per bucket, 2-edge ILP: Apack[dst][seg] = sum conj(xf[src])*rf[typ]*norm
__global__ __launch_bounds__(256) void k_reduce(
    const u16* __restrict__ xfh, const u16* __restrict__ rfh,
    const int4* __restrict__ recs, const int* __restrict__ base,
    u16* __restrict__ Ap) {
  int w = threadIdx.x >> 6, lane = threadIdx.x & 63;
  int b = blockIdx.x * 4 + w;
  int start = base[b], end = base[b + 1];
  float a0 = 0, a1 = 0, a2 = 0, a3 = 0;
  float nyr = 0, nyi = 0;
  int p = start;
  for (; p + 1 < end; p += 2) {
    int4 r0 = recs[p], r1 = recs[p + 1];
    float nm0 = __int_as_float(r0.z), nm1 = __int_as_float(r1.z);
    const u16* xp0 = xfh + (size_t)r0.x * NFP;
    const u16* rp0 = rfh + (size_t)r0.y * NFP;
    const u16* xp1 = xfh + (size_t)r1.x * NFP;
    const u16* rp1 = rfh + (size_t)r1.y * NFP;
    ushort4 xv0 = *(const ushort4*)(xp0 + 4 * lane);
    ushort4 xv1 = *(const ushort4*)(xp1 + 4 * lane);
    ushort4 rv0 = *(const ushort4*)(rp0 + 4 * lane);
    ushort4 rv1 = *(const ushort4*)(rp1 + 4 * lane);
    unsigned int xn0 = 0, xn1 = 0, rn0 = 0, rn1 = 0;
    if (lane == 0) {
      xn0 = *(const unsigned int*)(xp0 + 256);
      xn1 = *(const unsigned int*)(xp1 + 256);
      rn0 = *(const unsigned int*)(rp0 + 256);
      rn1 = *(const unsigned int*)(rp1 + 256);
    }
    {
      float xr0 = bu2f(xv0.x), xi0 = bu2f(xv0.y), xr1 = bu2f(xv0.z), xi1 = bu2f(xv0.w);
      float rr0 = bu2f(rv0.x), ri0 = bu2f(rv0.y), rr1 = bu2f(rv0.z), ri1 = bu2f(rv0.w);
      a0 += (xr0 * rr0 + xi0 * ri0) * nm0;
      a1 += (xr0 * ri0 - xi0 * rr0) * nm0;
      a2 += (xr1 * rr1 + xi1 * ri1) * nm0;
      a3 += (xr1 * ri1 - xi1 * rr1) * nm0;
      if (lane == 0) {
        float ar = bu2f((u16)xn0), ai = bu2f((u16)(xn0 >> 16));
        float br = bu2f((u16)rn0), bi = bu2f((u16)(rn0 >> 16));
        nyr += (ar * br + ai * bi) * nm0;
        nyi += (ar * bi - ai * br) * nm0;
      }
    }
    {
      float xr0 = bu2f(xv1.x), xi0 = bu2f(xv1.y), xr1 = bu2f(xv1.z), xi1 = bu2f(xv1.w);
      float rr0 = bu2f(rv1.x), ri0 = bu2f(rv1.y), rr1 = bu2f(rv1.z), ri1 = bu2f(rv1.w);
      a0 += (xr0 * rr0 + xi0 * ri0) * nm1;
      a1 += (xr0 * ri0 - xi0 * rr0) * nm1;
      a2 += (xr1 * rr1 + xi1 * ri1) * nm1;
      a3 += (xr1 * ri1 - xi1 * rr1) * nm1;
      if (lane == 0) {
        float ar = bu2f((u16)xn1), ai = bu2f((u16)(xn1 >> 16));
        float br = bu2f((u16)rn1), bi = bu2f((u16)(rn1 >> 16));
        nyr += (ar * br + ai * bi) * nm1;
        nyi += (ar * bi - ai * br) * nm1;
      }
    }
  }
  if (p < end) {
    int4 r0 = recs[p];
    float nm0 = __int_as_float(r0.z);
    const u16* xp0 = xfh + (size_t)r0.x * NFP;
    const u16* rp0 = rfh + (size_t)r0.y * NFP;
    ushort4 xv0 = *(const ushort4*)(xp0 + 4 * lane);
    ushort4 rv0 = *(const ushort4*)(rp0 + 4 * lane);
    float xr0 = bu2f(xv0.x), xi0 = bu2f(xv0.y), xr1 = bu2f(xv0.z), xi1 = bu2f(xv0.w);
    float rr0 = bu2f(rv0.x), ri0 = bu2f(rv0.y), rr1 = bu2f(rv0.z), ri1 = bu2f(rv0.w);
    a0 += (xr0 * rr0 + xi0 * ri0) * nm0;
    a1 += (xr0 * ri0 - xi0 * rr0) * nm0;
    a2 += (xr1 * rr1 + xi1 * ri1) * nm0;
    a3 += (xr1 * ri1 - xi1 * rr1) * nm0;
    if (lane == 0) {
      unsigned int xn0 = *(const unsigned int*)(xp0 + 256);
      unsigned int rn0 = *(const unsigned int*)(rp0 + 256);
      float ar = bu2f((u16)xn0), ai = bu2f((u16)(xn0 >> 16));
      float br = bu2f((u16)rn0), bi = bu2f((u16)(rn0 >> 16));
      nyr += (ar * br + ai * bi) * nm0;
      nyi += (ar * bi - ai * br) * nm0;
    }
  }
  u16* tp = Ap + ((b < NN) ? (size_t)b * KP : (size_t)(b - NN) * KP + 258);
  *(unsigned int*)(tp + 4 * lane)     = pk2(a0, a1);
  *(unsigned int*)(tp + 4 * lane + 2) = pk2(a2, a3);
  if (lane == 0) *(unsigned int*)(tp + 256) = pk2(nyr, nyi);
}

// MFMA GEMM: dout[80000][256] = Apack[80000][832]bf16 x Bt^T + bias
// global_load_lds staging (16B), pre-swizzled source, LDS double-buffer
__global__ __launch_bounds__(256) void k_mgemm(
    const u16* __restrict__ Ap, const u16* __restrict__ Bt,
    const float* __restrict__ bias, float* __restrict__ dout) {
  __shared__ u16 sA[2 * 128 * 64];
  __shared__ u16 sB[2 * 128 * 64];
  int tid = threadIdx.x;
  int mt0 = (blockIdx.x >> 1) * 128;
  int nt0 = (blockIdx.x & 1) * 128;
  int w = tid >> 6, lane = tid & 63;
  int wm = (w & 1) * 64, wn = (w >> 1) * 64;
  int fr = lane & 15, fg = lane >> 4;
  // staging geometry: wave w stages stripes s=w*4+q (8 rows each); lane l -> row
  // s*8 + (l>>3), lds col-block (l&7), global col-block (l&7)^(row&7) [pre-swizzle]
  int srow = (lane >> 3);
  int lcb = lane & 7;

#define STG(buf, kb)                                                                 \
  {                                                                                  \
    _Pragma("unroll") for (int q = 0; q < 4; ++q) {                                  \
      int s = w * 4 + q;                                                             \
      int row = s * 8 + srow;                                                        \
      int cb = lcb ^ (row & 7);                                                      \
      gload16(Ap + (size_t)(mt0 + row) * KP + (kb) * 64 + cb * 8,                    \
              sA + (buf) * 8192 + s * 512);                                          \
      gload16(Bt + (size_t)(nt0 + row) * KP + (kb) * 64 + cb * 8,                    \
              sB + (buf) * 8192 + s * 512);                                          \
    }                                                                                \
  }

  f32x4 acc[4][4];
#pragma unroll
  for (int i = 0; i < 4; ++i)
#pragma unroll
    for (int j = 0; j < 4; ++j) acc[i][j] = (f32x4){0.f, 0.f, 0.f, 0.f};

  STG(0, 0)
  __syncthreads();
  int cur = 0;
  for (int kb = 0; kb < 13; ++kb) {
    if (kb + 1 < 13) STG(cur ^ 1, kb + 1)
#pragma unroll
    for (int ks = 0; ks < 2; ++ks) {
      bf16x8 af[4], bf_[4];
#pragma unroll
      for (int mt = 0; mt < 4; ++mt) {
        int r = wm + mt * 16 + fr;
        af[mt] = *(const bf16x8*)(sA + cur * 8192 + r * 64 +
                                  ((ks * 32 + fg * 8) ^ ((r & 7) * 8)));
      }
#pragma unroll
      for (int nt = 0; nt < 4; ++nt) {
        int r = wn + nt * 16 + fr;
        bf_[nt] = *(const bf16x8*)(sB + cur * 8192 + r * 64 +
                                   ((ks * 32 + fg * 8) ^ ((r & 7) * 8)));
      }
#pragma unroll
      for (int mt = 0; mt < 4; ++mt)
#pragma unroll
        for (int nt = 0; nt < 4; ++nt)
          acc[mt][nt] = __builtin_amdgcn_mfma_f32_16x16x32_bf16(af[mt], bf_[nt],
                                                                acc[mt][nt], 0, 0, 0);
    }
    __syncthreads();
    cur ^= 1;
  }
#undef STG

#pragma unroll
  for (int mt = 0; mt < 4; ++mt)
#pragma unroll
    for (int nt = 0; nt < 4; ++nt) {
      int cg = nt0 + wn + nt * 16 + fr;
      float bv = bias[cg];
#pragma unroll
      for (int j = 0; j < 4; ++j) {
        int rg = mt0 + wm + mt * 16 + fg * 4 + j;
        dout[(size_t)rg * DD + cg] = acc[mt][nt][j] + bv;
      }
    }
}

// per-channel sum / sumsq over dout rows
__global__ __launch_bounds__(256) void k_sums(const float* __restrict__ dout,
                                              float* __restrict__ sum1,
                                              float* __restrict__ sum2) {
  int t = threadIdx.x;
  int b = blockIdx.x;
  float s1 = 0.f, s2 = 0.f;
  for (int i = 0; i < 250; ++i) {
    float v = dout[(size_t)(b * 250 + i) * DD + t];
    s1 += v; s2 += v * v;
  }
  atomicAdd(&sum1[t], s1);
  atomicAdd(&sum2[t], s2);
}

__global__ void k_stats(const float* __restrict__ sum1, const float* __restrict__ sum2,
                        float* __restrict__ mean, float* __restrict__ rstd) {
  int c = threadIdx.x;
  float m = sum1[c] * (1.0f / (float)NN);
  float var = sum2[c] * (1.0f / (float)NN) - m * m;
  mean[c] = m;
  rstd[c] = rsqrtf(var + 1e-5f);
}

__global__ void k_norm(float* __restrict__ out, const float* __restrict__ mean,
                       const float* __restrict__ rstd) {
  size_t i4 = ((size_t)blockIdx.x * 256 + threadIdx.x) * 4;
  float4* p = (float4*)(out + i4);
  float4 v = *p;
  int c0 = (int)(i4 & 255);
  v.x = (v.x - mean[c0 + 0]) * rstd[c0 + 0];
  v.y = (v.y - mean[c0 + 1]) * rstd[c0 + 1];
  v.z = (v.z - mean[c0 + 2]) * rstd[c0 + 2];
  v.w = (v.w - mean[c0 + 3]) * rstd[c0 + 3];
  *p = v;
}

__global__ void k_rel(const float* __restrict__ rel, const float* __restrict__ wrel,
                      float* __restrict__ out2) {
  __shared__ float R[DD];
  int r = blockIdx.x, c = threadIdx.x;
  R[c] = rel[(size_t)r * DD + c];
  __syncthreads();
  float acc = 0.0f;
  for (int j = 0; j < DD; ++j)
    acc += R[j] * wrel[(size_t)j * DD + c];
  out2[(size_t)r * DD + c] = acc;
}

__global__ void k_fail(float* __restrict__ out, int n) {
  int i = blockIdx.x * 256 + threadIdx.x;
  if (i < n) out[i] = 1.0e6f;   // "workspace too small" marker
}

extern "C" void kernel_launch(void* const* d_in, const int* in_sizes, int n_in,
                              void* d_out, int out_size, void* d_ws, size_t ws_size,
                              hipStream_t stream) {
  (void)in_sizes; (void)n_in;
  const float* x      = (const float*)d_in[0];
  const float* rel    = (const float*)d_in[1];
  const int*   esrc   = (const int*)d_in[2];
  const int*   edst   = (const int*)d_in[3];
  const int*   etyp   = (const int*)d_in[4];
  const float* enorm  = (const float*)d_in[5];
  const float* in_w   = (const float*)d_in[6];
  const float* out_w  = (const float*)d_in[7];
  const float* loop_w = (const float*)d_in[8];
  const float* w_rel  = (const float*)d_in[9];
  const float* lr     = (const float*)d_in[10];
  const float* bias   = (const float*)d_in[11];
  float* dout = (float*)d_out;

  char* wsb = (char*)d_ws;
  size_t off = 0;
  u16* Apack = (u16*)(wsb + off); off += (size_t)NN * KP * 2;        // 133.1 MB
  u16* Bt    = (u16*)(wsb + off); off += (size_t)DD * KP * 2;        // 0.43 MB
  u16* xfh   = (u16*)(wsb + off); off += (size_t)NN * NFP * 2;       // 41.6 MB
  u16* rfh   = (u16*)(wsb + off); off += (size_t)NR * NFP * 2;       // 0.21 MB
  u16* xb    = (u16*)(wsb + off); off += (size_t)MT * DD * 2;        // 41.2 MB
  u16* Ft    = (u16*)(wsb + off); off += (size_t)DD * DD * 2;        // 0.13 MB
  int4* recs = (int4*)(wsb + off); off += (size_t)NE * 16;           // 12.8 MB (16B aligned)
  float* sum1  = (float*)(wsb + off); off += DD * 4;
  float* sum2  = (float*)(wsb + off); off += DD * 4;
  float* meanb = (float*)(wsb + off); off += DD * 4;
  float* rstdb = (float*)(wsb + off); off += DD * 4;
  int* cnt   = (int*)(wsb + off); off += (size_t)(NB + 1) * 4;
  int* baseA = (int*)(wsb + off); off += (size_t)(NB + 1) * 4;
  int* curA  = (int*)(wsb + off); off += (size_t)NB * 4;
  int* chT   = (int*)(wsb + off); off += 256 * 4;
  int* chO   = (int*)(wsb + off); off += 256 * 4;

  if (ws_size < off) {
    k_fail<<<(out_size + 255) / 256, 256, 0, stream>>>(dout, out_size);
    return;
  }

  hipMemsetAsync(cnt, 0, (NB + 1) * sizeof(int), stream);
  hipMemsetAsync(sum1, 0, 2 * DD * sizeof(float), stream);
  k_cvt<<<625, 256, 0, stream>>>(x, Apack, xb);
  k_cvtr<<<NR, 256, 0, stream>>>(rel, xb);
  k_build_f<<<256, 256, 0, stream>>>(Ft);
  k_build_m<<<516, 256, 0, stream>>>(in_w, out_w, Bt);
  k_build_q<<<256, 256, 0, stream>>>(lr, loop_w, Bt);
  k_dft<<<629 * 2, 256, 0, stream>>>(xb, Ft, xfh, rfh);
  k_nyq<<<(MT + 3) / 4, 256, 0, stream>>>(x, rel, xfh, rfh);
  k_hist<<<NE / 256, 256, 0, stream>>>(edst, cnt);
  k_scan1<<<NCH, 256, 0, stream>>>(cnt, baseA, chT);
  k_scan2<<<1, 256, 0, stream>>>(chT, chO);
  k_scan3<<<(NB + 255) / 256, 256, 0, stream>>>(baseA, chO, curA);
  k_scatter<<<NE / 256, 256, 0, stream>>>(esrc, edst, etyp, enorm, curA, recs);
  k_reduce<<<NB / 4, 256, 0, stream>>>(xfh, rfh, recs, baseA, Apack);
  k_mgemm<<<(NN / 128) * 2, 256, 0, stream>>>(Apack, Bt, bias, dout);
  k_sums<<<320, 256, 0, stream>>>(dout, sum1, sum2);
  k_stats<<<1, 256, 0, stream>>>(sum1, sum2, meanb, rstdb);
  k_norm<<<NN * DD / 4 / 256, 256, 0, stream>>>(dout, meanb, rstdb);
  k_rel<<<NR, 256, 0, stream>>>(rel, w_rel, dout + (size_t)NN * DD);
}

// Round 7
// 442.464 us; speedup vs baseline: 11.3191x; 1.1584x over previous
//
#include <hip/hip_runtime.h>

#define NN 80000     // nodes
#define NE 800000    // edges
#define EH 400000    // first half -> in_w
#define NR 400       // relations
#define DD 256       // feature dim
#define NFP 260      // freq row stride in bf16 elems (129 complex bins = 258 used)
#define KT 772       // 258 + 258 + 256 logical GEMM K
#define KP 832       // K padded to 13*64
#define NB 160000    // sort buckets: dir*NN + dst
#define NCH 157      // ceil(NB/1024) scan chunks
#define MT 80400     // total DFT rows (x + rel)
#define PI2 6.283185307179586f

typedef unsigned short u16;
typedef __attribute__((ext_vector_type(8))) short bf16x8;
typedef __attribute__((ext_vector_type(4))) float f32x4;

static __device__ __forceinline__ float bu2f(u16 u) {
  return __uint_as_float(((unsigned int)u) << 16);
}
static __device__ __forceinline__ u16 f2bu(float f) {
  unsigned int x = __float_as_uint(f);
  x += 0x7fffu + ((x >> 16) & 1u);   // RNE
  return (u16)(x >> 16);
}
static __device__ __forceinline__ unsigned int pk2(float a, float b) {
  return (unsigned int)f2bu(a) | ((unsigned int)f2bu(b) << 16);
}
// async global->LDS 16B: lds dest = wave-uniform base + lane*16
static __device__ __forceinline__ void gload16(const void* g, void* l) {
  __builtin_amdgcn_global_load_lds(
      (const __attribute__((address_space(1))) unsigned int*)g,
      (__attribute__((address_space(3))) unsigned int*)l, 16, 0, 0);
}

// DFT coefficient matrix: Ft[c][j]; c=2k -> cos(2pi jk/256), c=2k+1 -> -sin(2pi jk/256)
__global__ void k_build_f(u16* __restrict__ Ft) {
  int c = blockIdx.x, j = threadIdx.x;
  int k = c >> 1;
  int m = (j * k) & 255;               // exact mod-256 angle reduction
  float th = -PI2 * (float)m * (1.0f / 256.0f);
  float v = (c & 1) ? sinf(th) : cosf(th);
  Ft[c * 256 + j] = f2bu(v);
}

// Bt rows: Bt[c][t] = (a_k/768)*[cos|-sin](2*pi*j*k/256) dot W[j][c], t=0..515
__global__ void k_build_m(const float* __restrict__ in_w, const float* __restrict__ out_w,
                          u16* __restrict__ Bt) {
  int t = blockIdx.x;                  // 0..515
  int c = threadIdx.x;                 // 0..255
  const float* W = (t < 258) ? in_w : out_w;
  int tp = (t < 258) ? t : t - 258;
  int k = tp >> 1, im = tp & 1;
  float a = (k == 0 || k == 128) ? 1.0f : 2.0f;
  float scale = a * (1.0f / (256.0f * 3.0f));
  float th = -PI2 * (float)k * (1.0f / 256.0f);
  float wr = cosf(th), wi = sinf(th);
  float zr = 1.0f, zi = 0.0f;
  float acc = 0.0f;
  for (int j = 0; j < DD; ++j) {
    float coef = im ? zi : zr;
    acc += coef * W[(size_t)j * DD + c];
    float nzr = zr * wr - zi * wi; zi = zr * wi + zi * wr; zr = nzr;
  }
  Bt[(size_t)c * KP + t] = f2bu(scale * acc);
}

// Bt[c][516+j] = (1/3) sum_k lr[(j+k)%256] * loop_w[k][c]; also zero K-pad
__global__ void k_build_q(const float* __restrict__ lr, const float* __restrict__ loop_w,
                          u16* __restrict__ Bt) {
  __shared__ float L[DD];
  int j = blockIdx.x, c = threadIdx.x;
  L[c] = lr[c];
  __syncthreads();
  float acc = 0.0f;
  for (int k2 = 0; k2 < DD; ++k2)
    acc += L[(j + k2) & 255] * loop_w[(size_t)k2 * DD + c];
  Bt[(size_t)c * KP + 516 + j] = f2bu(acc * (1.0f / 3.0f));
  if (j < KP - KT) Bt[(size_t)c * KP + KT + j] = 0;
}

// wave-per-row: x -> bf16 (xb + Apack cols 516..771, zero pad) + Nyquist into xfh
__global__ __launch_bounds__(256) void k_cvt(const float* __restrict__ x,
                                             u16* __restrict__ Ap, u16* __restrict__ xb,
                                             u16* __restrict__ xfh) {
  int w = threadIdx.x >> 6, lane = threadIdx.x & 63;
  size_t row = (size_t)blockIdx.x * 4 + w;        // 20000 blocks
  float4 v = *(const float4*)(x + row * DD + 4 * lane);
  ushort4 pk;
  pk.x = f2bu(v.x); pk.y = f2bu(v.y); pk.z = f2bu(v.z); pk.w = f2bu(v.w);
  *(ushort4*)(xb + row * DD + 4 * lane) = pk;
  *(ushort4*)(Ap + row * KP + 516 + 4 * lane) = pk;
  if (lane < 15) *(uint2*)(Ap + row * KP + KT + 4 * lane) = make_uint2(0u, 0u);
  float s = v.x - v.y + v.z - v.w;
#pragma unroll
  for (int off = 32; off > 0; off >>= 1) s += __shfl_xor(s, off);
  if (lane == 0) {
    xfh[row * NFP + 256] = f2bu(s);
    xfh[row * NFP + 257] = 0;
  }
}

// wave-per-row: rel -> bf16 xb rows NN.. + Nyquist into rfh
__global__ __launch_bounds__(256) void k_cvtr(const float* __restrict__ rel,
                                              u16* __restrict__ xb, u16* __restrict__ rfh) {
  int w = threadIdx.x >> 6, lane = threadIdx.x & 63;
  size_t row = (size_t)blockIdx.x * 4 + w;        // 100 blocks
  float4 v = *(const float4*)(rel + row * DD + 4 * lane);
  ushort4 pk;
  pk.x = f2bu(v.x); pk.y = f2bu(v.y); pk.z = f2bu(v.z); pk.w = f2bu(v.w);
  *(ushort4*)(xb + (NN + row) * DD + 4 * lane) = pk;
  float s = v.x - v.y + v.z - v.w;
#pragma unroll
  for (int off = 32; off > 0; off >>= 1) s += __shfl_xor(s, off);
  if (lane == 0) {
    rfh[row * NFP + 256] = f2bu(s);
    rfh[row * NFP + 257] = 0;
  }
}

// MFMA DFT: XF[MT][256] = xb[MT][256] @ Ft^T, bf16 out to xfh/rfh (stride NFP)
__global__ __launch_bounds__(256) void k_dft(
    const u16* __restrict__ xb, const u16* __restrict__ Ft,
    u16* __restrict__ xfh, u16* __restrict__ rfh) {
  __shared__ u16 sA[128 * 64];
  __shared__ u16 sB[128 * 64];
  int tid = threadIdx.x;
  int mt0 = (int)(blockIdx.x >> 1) * 128;
  int nt0 = (blockIdx.x & 1) * 128;
  int w = tid >> 6, lane = tid & 63;
  int wm = (w & 1) * 64, wn = (w >> 1) * 64;
  int fr = lane & 15, fg = lane >> 4;
  int rbase = tid >> 3;
  int cbe = (tid & 7) * 8;
  int wadr = rbase * 64 + (cbe ^ ((rbase & 7) * 8));

  f32x4 acc[4][4];
#pragma unroll
  for (int i = 0; i < 4; ++i)
#pragma unroll
    for (int j = 0; j < 4; ++j) acc[i][j] = (f32x4){0.f, 0.f, 0.f, 0.f};

  bf16x8 ra[4], rb[4];
#define LOADT(kb)                                                                   \
  {                                                                                 \
    _Pragma("unroll") for (int q = 0; q < 4; ++q) {                                 \
      int rr = mt0 + rbase + q * 32; if (rr > MT - 1) rr = MT - 1;                  \
      ra[q] = *(const bf16x8*)(xb + (size_t)rr * DD + (kb) * 64 + cbe);             \
      rb[q] = *(const bf16x8*)(Ft + (size_t)(nt0 + rbase + q * 32) * DD + (kb) * 64 + cbe); \
    }                                                                               \
  }

  LOADT(0)
  for (int kb = 0; kb < 4; ++kb) {
    __syncthreads();
#pragma unroll
    for (int q = 0; q < 4; ++q) {
      *(bf16x8*)(sA + q * 2048 + wadr) = ra[q];
      *(bf16x8*)(sB + q * 2048 + wadr) = rb[q];
    }
    __syncthreads();
    if (kb + 1 < 4) LOADT(kb + 1)
#pragma unroll
    for (int ks = 0; ks < 2; ++ks) {
      bf16x8 af[4], bf_[4];
#pragma unroll
      for (int mt = 0; mt < 4; ++mt) {
        int r = wm + mt * 16 + fr;
        af[mt] = *(const bf16x8*)(sA + r * 64 + ((ks * 32 + fg * 8) ^ ((r & 7) * 8)));
      }
#pragma unroll
      for (int nt = 0; nt < 4; ++nt) {
        int r = wn + nt * 16 + fr;
        bf_[nt] = *(const bf16x8*)(sB + r * 64 + ((ks * 32 + fg * 8) ^ ((r & 7) * 8)));
      }
#pragma unroll
      for (int mt = 0; mt < 4; ++mt)
#pragma unroll
        for (int nt = 0; nt < 4; ++nt)
          acc[mt][nt] = __builtin_amdgcn_mfma_f32_16x16x32_bf16(af[mt], bf_[nt],
                                                                acc[mt][nt], 0, 0, 0);
    }
  }
#undef LOADT

#pragma unroll
  for (int mt = 0; mt < 4; ++mt)
#pragma unroll
    for (int nt = 0; nt < 4; ++nt) {
      int cg = nt0 + wn + nt * 16 + fr;
#pragma unroll
      for (int j = 0; j < 4; ++j) {
        int rg = mt0 + wm + mt * 16 + fg * 4 + j;
        u16 val = f2bu(acc[mt][nt][j]);
        if (rg < NN)      xfh[(size_t)rg * NFP + cg] = val;
        else if (rg < MT) rfh[(size_t)(rg - NN) * NFP + cg] = val;
      }
    }
}

// ---------- counting sort by key = (e>=EH)*NN + dst ----------
__global__ void k_hist(const int* __restrict__ edst, int* __restrict__ cnt) {
  int e = blockIdx.x * 256 + threadIdx.x;
  int key = edst[e] + ((e >= EH) ? NN : 0);
  atomicAdd(&cnt[key], 1);
}

__global__ __launch_bounds__(256) void k_scan1(const int* __restrict__ cnt,
                                               int* __restrict__ base,
                                               int* __restrict__ chunkTot) {
  __shared__ int wsum[4];
  int t = threadIdx.x;
  int g0 = blockIdx.x * 1024 + t * 4;
  int v[4], ex[4], s = 0;
#pragma unroll
  for (int j = 0; j < 4; ++j) v[j] = (g0 + j < NB) ? cnt[g0 + j] : 0;
#pragma unroll
  for (int j = 0; j < 4; ++j) { ex[j] = s; s += v[j]; }
  int lane = t & 63, w = t >> 6;
  int inc = s;
  for (int off = 1; off < 64; off <<= 1) {
    int n = __shfl_up(inc, off);
    if (lane >= off) inc += n;
  }
  if (lane == 63) wsum[w] = inc;
  __syncthreads();
  int woff = 0;
  for (int i = 0; i < w; ++i) woff += wsum[i];
  int exth = woff + inc - s;
#pragma unroll
  for (int j = 0; j < 4; ++j)
    if (g0 + j < NB) base[g0 + j] = exth + ex[j];
  if (t == 255) chunkTot[blockIdx.x] = woff + inc;
}

__global__ __launch_bounds__(256) void k_scan2(const int* __restrict__ chunkTot,
                                               int* __restrict__ chunkOff) {
  __shared__ int wsum[4];
  int t = threadIdx.x;
  int v = (t < NCH) ? chunkTot[t] : 0;
  int lane = t & 63, w = t >> 6;
  int inc = v;
  for (int off = 1; off < 64; off <<= 1) {
    int n = __shfl_up(inc, off);
    if (lane >= off) inc += n;
  }
  if (lane == 63) wsum[w] = inc;
  __syncthreads();
  int woff = 0;
  for (int i = 0; i < w; ++i) woff += wsum[i];
  if (t < NCH) chunkOff[t] = woff + inc - v;
}

__global__ void k_scan3(int* __restrict__ base, const int* __restrict__ chunkOff,
                        int* __restrict__ cursor) {
  int i = blockIdx.x * 256 + threadIdx.x;
  if (i < NB) {
    int b = base[i] + chunkOff[i >> 10];
    base[i] = b;
    cursor[i] = b;
  }
  if (i == 0) base[NB] = NE;
}

// scatter packed records: (src, typ, norm_bits, 0) -> sorted position
__global__ void k_scatter(const int* __restrict__ esrc, const int* __restrict__ edst,
                          const int* __restrict__ etyp, const float* __restrict__ enorm,
                          int* __restrict__ cursor, int4* __restrict__ recs) {
  int e = blockIdx.x * 256 + threadIdx.x;
  int key = edst[e] + ((e >= EH) ? NN : 0);
  int pos = atomicAdd(&cursor[key], 1);
  recs[pos] = make_int4(esrc[e], etyp[e], __float_as_int(enorm[e]), 0);
}

// one wave per bucket, 4-edge ILP: Apack[dst][seg] = sum conj(xf[src])*rf[typ]*norm
__global__ __launch_bounds__(256) void k_reduce(
    const u16* __restrict__ xfh, const u16* __restrict__ rfh,
    const int4* __restrict__ recs, const int* __restrict__ base,
    u16* __restrict__ Ap) {
  int w = threadIdx.x >> 6, lane = threadIdx.x & 63;
  int b = blockIdx.x * 4 + w;
  int start = base[b], end = base[b + 1];
  float a0 = 0, a1 = 0, a2 = 0, a3 = 0;
  float nyr = 0, nyi = 0;
  int p = start;
  for (; p + 3 < end; p += 4) {
    ushort4 xv[4], rv[4];
    float nm[4];
    unsigned int xn[4], rn[4];
#pragma unroll
    for (int u = 0; u < 4; ++u) {
      int4 rc = recs[p + u];
      nm[u] = __int_as_float(rc.z);
      const u16* xp = xfh + (size_t)rc.x * NFP;
      const u16* rp = rfh + (size_t)rc.y * NFP;
      xv[u] = *(const ushort4*)(xp + 4 * lane);
      rv[u] = *(const ushort4*)(rp + 4 * lane);
      if (lane == 0) {
        xn[u] = *(const unsigned int*)(xp + 256);
        rn[u] = *(const unsigned int*)(rp + 256);
      }
    }
#pragma unroll
    for (int u = 0; u < 4; ++u) {
      float xr0 = bu2f(xv[u].x), xi0 = bu2f(xv[u].y);
      float xr1 = bu2f(xv[u].z), xi1 = bu2f(xv[u].w);
      float rr0 = bu2f(rv[u].x), ri0 = bu2f(rv[u].y);
      float rr1 = bu2f(rv[u].z), ri1 = bu2f(rv[u].w);
      a0 += (xr0 * rr0 + xi0 * ri0) * nm[u];
      a1 += (xr0 * ri0 - xi0 * rr0) * nm[u];
      a2 += (xr1 * rr1 + xi1 * ri1) * nm[u];
      a3 += (xr1 * ri1 - xi1 * rr1) * nm[u];
      if (lane == 0) {
        float ar = bu2f((u16)xn[u]), ai = bu2f((u16)(xn[u] >> 16));
        float br = bu2f((u16)rn[u]), bi = bu2f((u16)(rn[u] >> 16));
        nyr += (ar * br + ai * bi) * nm[u];
        nyi += (ar * bi - ai * br) * nm[u];
      }
    }
  }
  for (; p < end; ++p) {
    int4 rc = recs[p];
    float nm0 = __int_as_float(rc.z);
    const u16* xp = xfh + (size_t)rc.x * NFP;
    const u16* rp = rfh + (size_t)rc.y * NFP;
    ushort4 xv0 = *(const ushort4*)(xp + 4 * lane);
    ushort4 rv0 = *(const ushort4*)(rp + 4 * lane);
    float xr0 = bu2f(xv0.x), xi0 = bu2f(xv0.y), xr1 = bu2f(xv0.z), xi1 = bu2f(xv0.w);
    float rr0 = bu2f(rv0.x), ri0 = bu2f(rv0.y), rr1 = bu2f(rv0.z), ri1 = bu2f(rv0.w);
    a0 += (xr0 * rr0 + xi0 * ri0) * nm0;
    a1 += (xr0 * ri0 - xi0 * rr0) * nm0;
    a2 += (xr1 * rr1 + xi1 * ri1) * nm0;
    a3 += (xr1 * ri1 - xi1 * rr1) * nm0;
    if (lane == 0) {
      unsigned int xn0 = *(const unsigned int*)(xp + 256);
      unsigned int rn0 = *(const unsigned int*)(rp + 256);
      float ar = bu2f((u16)xn0), ai = bu2f((u16)(xn0 >> 16));
      float br = bu2f((u16)rn0), bi = bu2f((u16)(rn0 >> 16));
      nyr += (ar * br + ai * bi) * nm0;
      nyi += (ar * bi - ai * br) * nm0;
    }
  }
  u16* tp = Ap + ((b < NN) ? (size_t)b * KP : (size_t)(b - NN) * KP + 258);
  *(unsigned int*)(tp + 4 * lane)     = pk2(a0, a1);
  *(unsigned int*)(tp + 4 * lane + 2) = pk2(a2, a3);
  if (lane == 0) *(unsigned int*)(tp + 256) = pk2(nyr, nyi);
}

// MFMA GEMM + fused BN partial sums:
// dout = Apack x Bt^T + bias ; per-channel sum/sumsq via LDS reduce + atomics
__global__ __launch_bounds__(256) void k_mgemm(
    const u16* __restrict__ Ap, const u16* __restrict__ Bt,
    const float* __restrict__ bias, float* __restrict__ dout,
    float* __restrict__ sum1, float* __restrict__ sum2) {
  __shared__ u16 sA[2 * 128 * 64];
  __shared__ u16 sB[2 * 128 * 64];
  __shared__ float sS1[128], sS2[128];
  int tid = threadIdx.x;
  int mt0 = (blockIdx.x >> 1) * 128;
  int nt0 = (blockIdx.x & 1) * 128;
  int w = tid >> 6, lane = tid & 63;
  int wm = (w & 1) * 64, wn = (w >> 1) * 64;
  int fr = lane & 15, fg = lane >> 4;
  int srow = (lane >> 3);
  int lcb = lane & 7;
  if (tid < 128) { sS1[tid] = 0.f; sS2[tid] = 0.f; }

#define STG(buf, kb)                                                                 \
  {                                                                                  \
    _Pragma("unroll") for (int q = 0; q < 4; ++q) {                                  \
      int s = w * 4 + q;                                                             \
      int row = s * 8 + srow;                                                        \
      int cb = lcb ^ (row & 7);                                                      \
      gload16(Ap + (size_t)(mt0 + row) * KP + (kb) * 64 + cb * 8,                    \
              sA + (buf) * 8192 + s * 512);                                          \
      gload16(Bt + (size_t)(nt0 + row) * KP + (kb) * 64 + cb * 8,                    \
              sB + (buf) * 8192 + s * 512);                                          \
    }                                                                                \
  }

  f32x4 acc[4][4];
#pragma unroll
  for (int i = 0; i < 4; ++i)
#pragma unroll
    for (int j = 0; j < 4; ++j) acc[i][j] = (f32x4){0.f, 0.f, 0.f, 0.f};

  STG(0, 0)
  __syncthreads();
  int cur = 0;
  for (int kb = 0; kb < 13; ++kb) {
    if (kb + 1 < 13) STG(cur ^ 1, kb + 1)
#pragma unroll
    for (int ks = 0; ks < 2; ++ks) {
      bf16x8 af[4], bf_[4];
#pragma unroll
      for (int mt = 0; mt < 4; ++mt) {
        int r = wm + mt * 16 + fr;
        af[mt] = *(const bf16x8*)(sA + cur * 8192 + r * 64 +
                                  ((ks * 32 + fg * 8) ^ ((r & 7) * 8)));
      }
#pragma unroll
      for (int nt = 0; nt < 4; ++nt) {
        int r = wn + nt * 16 + fr;
        bf_[nt] = *(const bf16x8*)(sB + cur * 8192 + r * 64 +
                                   ((ks * 32 + fg * 8) ^ ((r & 7) * 8)));
      }
#pragma unroll
      for (int mt = 0; mt < 4; ++mt)
#pragma unroll
        for (int nt = 0; nt < 4; ++nt)
          acc[mt][nt] = __builtin_amdgcn_mfma_f32_16x16x32_bf16(af[mt], bf_[nt],
                                                                acc[mt][nt], 0, 0, 0);
    }
    __syncthreads();
    cur ^= 1;
  }
#undef STG

  float s1[4] = {0.f, 0.f, 0.f, 0.f}, s2[4] = {0.f, 0.f, 0.f, 0.f};
#pragma unroll
  for (int nt = 0; nt < 4; ++nt) {
    int cg = nt0 + wn + nt * 16 + fr;
    float bv = bias[cg];
#pragma unroll
    for (int mt = 0; mt < 4; ++mt) {
#pragma unroll
      for (int j = 0; j < 4; ++j) {
        int rg = mt0 + wm + mt * 16 + fg * 4 + j;
        float val = acc[mt][nt][j] + bv;
        dout[(size_t)rg * DD + cg] = val;
        s1[nt] += val;
        s2[nt] += val * val;
      }
    }
  }
#pragma unroll
  for (int nt = 0; nt < 4; ++nt) {
    atomicAdd(&sS1[wn + nt * 16 + fr], s1[nt]);
    atomicAdd(&sS2[wn + nt * 16 + fr], s2[nt]);
  }
  __syncthreads();
  if (tid < 128) {
    atomicAdd(&sum1[nt0 + tid], sS1[tid]);
    atomicAdd(&sum2[nt0 + tid], sS2[tid]);
  }
}

__global__ void k_stats(const float* __restrict__ sum1, const float* __restrict__ sum2,
                        float* __restrict__ mean, float* __restrict__ rstd) {
  int c = threadIdx.x;
  float m = sum1[c] * (1.0f / (float)NN);
  float var = sum2[c] * (1.0f / (float)NN) - m * m;
  mean[c] = m;
  rstd[c] = rsqrtf(var + 1e-5f);
}

__global__ void k_norm(float* __restrict__ out, const float* __restrict__ mean,
                       const float* __restrict__ rstd) {
  size_t i4 = ((size_t)blockIdx.x * 256 + threadIdx.x) * 4;
  float4* p = (float4*)(out + i4);
  float4 v = *p;
  int c0 = (int)(i4 & 255);
  v.x = (v.x - mean[c0 + 0]) * rstd[c0 + 0];
  v.y = (v.y - mean[c0 + 1]) * rstd[c0 + 1];
  v.z = (v.z - mean[c0 + 2]) * rstd[c0 + 2];
  v.w = (v.w - mean[c0 + 3]) * rstd[c0 + 3];
  *p = v;
}

__global__ void k_rel(const float* __restrict__ rel, const float* __restrict__ wrel,
                      float* __restrict__ out2) {
  __shared__ float R[DD];
  int r = blockIdx.x, c = threadIdx.x;
  R[c] = rel[(size_t)r * DD + c];
  __syncthreads();
  float acc = 0.0f;
  for (int j = 0; j < DD; ++j)
    acc += R[j] * wrel[(size_t)j * DD + c];
  out2[(size_t)r * DD + c] = acc;
}

__global__ void k_fail(float* __restrict__ out, int n) {
  int i = blockIdx.x * 256 + threadIdx.x;
  if (i < n) out[i] = 1.0e6f;   // "workspace too small" marker
}

extern "C" void kernel_launch(void* const* d_in, const int* in_sizes, int n_in,
                              void* d_out, int out_size, void* d_ws, size_t ws_size,
                              hipStream_t stream) {
  (void)in_sizes; (void)n_in;
  const float* x      = (const float*)d_in[0];
  const float* rel    = (const float*)d_in[1];
  const int*   esrc   = (const int*)d_in[2];
  const int*   edst   = (const int*)d_in[3];
  const int*   etyp   = (const int*)d_in[4];
  const float* enorm  = (const float*)d_in[5];
  const float* in_w   = (const float*)d_in[6];
  const float* out_w  = (const float*)d_in[7];
  const float* loop_w = (const float*)d_in[8];
  const float* w_rel  = (const float*)d_in[9];
  const float* lr     = (const float*)d_in[10];
  const float* bias   = (const float*)d_in[11];
  float* dout = (float*)d_out;

  char* wsb = (char*)d_ws;
  size_t off = 0;
  u16* Apack = (u16*)(wsb + off); off += (size_t)NN * KP * 2;        // 133.1 MB
  u16* Bt    = (u16*)(wsb + off); off += (size_t)DD * KP * 2;        // 0.43 MB
  u16* xfh   = (u16*)(wsb + off); off += (size_t)NN * NFP * 2;       // 41.6 MB
  u16* rfh   = (u16*)(wsb + off); off += (size_t)NR * NFP * 2;       // 0.21 MB
  u16* xb    = (u16*)(wsb + off); off += (size_t)MT * DD * 2;        // 41.2 MB
  u16* Ft    = (u16*)(wsb + off); off += (size_t)DD * DD * 2;        // 0.13 MB
  int4* recs = (int4*)(wsb + off); off += (size_t)NE * 16;           // 12.8 MB
  float* sum1  = (float*)(wsb + off); off += DD * 4;
  float* sum2  = (float*)(wsb + off); off += DD * 4;
  float* meanb = (float*)(wsb + off); off += DD * 4;
  float* rstdb = (float*)(wsb + off); off += DD * 4;
  int* cnt   = (int*)(wsb + off); off += (size_t)(NB + 1) * 4;
  int* baseA = (int*)(wsb + off); off += (size_t)(NB + 1) * 4;
  int* curA  = (int*)(wsb + off); off += (size_t)NB * 4;
  int* chT   = (int*)(wsb + off); off += 256 * 4;
  int* chO   = (int*)(wsb + off); off += 256 * 4;

  if (ws_size < off) {
    k_fail<<<(out_size + 255) / 256, 256, 0, stream>>>(dout, out_size);
    return;
  }

  hipMemsetAsync(cnt, 0, (NB + 1) * sizeof(int), stream);
  hipMemsetAsync(sum1, 0, 2 * DD * sizeof(float), stream);
  k_cvt<<<NN / 4, 256, 0, stream>>>(x, Apack, xb, xfh);
  k_cvtr<<<NR / 4, 256, 0, stream>>>(rel, xb, rfh);
  k_build_f<<<256, 256, 0, stream>>>(Ft);
  k_build_m<<<516, 256, 0, stream>>>(in_w, out_w, Bt);
  k_build_q<<<256, 256, 0, stream>>>(lr, loop_w, Bt);
  k_dft<<<629 * 2, 256, 0, stream>>>(xb, Ft, xfh, rfh);
  k_hist<<<NE / 256, 256, 0, stream>>>(edst, cnt);
  k_scan1<<<NCH, 256, 0, stream>>>(cnt, baseA, chT);
  k_scan2<<<1, 256, 0, stream>>>(chT, chO);
  k_scan3<<<(NB + 255) / 256, 256, 0, stream>>>(baseA, chO, curA);
  k_scatter<<<NE / 256, 256, 0, stream>>>(esrc, edst, etyp, enorm, curA, recs);
  k_reduce<<<NB / 4, 256, 0, stream>>>(xfh, rfh, recs, baseA, Apack);
  k_mgemm<<<(NN / 128) * 2, 256, 0, stream>>>(Apack, Bt, bias, dout, sum1, sum2);
  k_stats<<<1, 256, 0, stream>>>(sum1, sum2, meanb, rstdb);
  k_norm<<<NN * DD / 4 / 256, 256, 0, stream>>>(dout, meanb, rstdb);
  k_rel<<<NR, 256, 0, stream>>>(rel, w_rel, dout + (size_t)NN * DD);
}

// Round 8
// 381.639 us; speedup vs baseline: 13.1231x; 1.1594x over previous
//
#include <hip/hip_runtime.h>

#define NN 80000     // nodes
#define NE 800000    // edges
#define EH 400000    // first half -> in_w
#define NR 400       // relations
#define DD 256       // feature dim
#define FD 256       // freq row: col0=bin0.re, col1=bin128.re, 2k/2k+1=bin k
#define KP 768       // GEMM K = 256*3 (in | out | self), = 12*64 exactly
#define NB 160000    // sort buckets: dir*NN + dst
#define NCH 157      // ceil(NB/1024) scan chunks
#define MT 80400     // total DFT rows (x + rel)
#define PI2 6.283185307179586f

typedef unsigned short u16;
typedef __attribute__((ext_vector_type(8))) short bf16x8;
typedef __attribute__((ext_vector_type(4))) float f32x4;

static __device__ __forceinline__ float bu2f(u16 u) {
  return __uint_as_float(((unsigned int)u) << 16);
}
static __device__ __forceinline__ u16 f2bu(float f) {
  unsigned int x = __float_as_uint(f);
  x += 0x7fffu + ((x >> 16) & 1u);   // RNE
  return (u16)(x >> 16);
}
static __device__ __forceinline__ unsigned int pk2(float a, float b) {
  return (unsigned int)f2bu(a) | ((unsigned int)f2bu(b) << 16);
}
// async global->LDS 16B: lds dest = wave-uniform base + lane*16
static __device__ __forceinline__ void gload16(const void* g, void* l) {
  __builtin_amdgcn_global_load_lds(
      (const __attribute__((address_space(1))) unsigned int*)g,
      (__attribute__((address_space(3))) unsigned int*)l, 16, 0, 0);
}

// DFT coefficient matrix Ft[c][j] (bf16, linear):
// c=0: 1 ; c=1: (-1)^j ; c>=2: k=c>>1, even->cos(2pi jk/256), odd->-sin
__global__ void k_build_f(u16* __restrict__ Ft) {
  int c = blockIdx.x, j = threadIdx.x;
  int k, im;
  if (c == 0)      { k = 0;   im = 0; }
  else if (c == 1) { k = 128; im = 0; }
  else             { k = c >> 1; im = c & 1; }
  int m = (j * k) & 255;               // exact mod-256 angle reduction
  float th = -PI2 * (float)m * (1.0f / 256.0f);
  float v = im ? sinf(th) : cosf(th);
  Ft[c * 256 + j] = f2bu(v);
}

// Bt[c][t], t<256: in_w, t<512: out_w. Bin t-layout matches Ft/reduce cols.
__global__ void k_build_m(const float* __restrict__ in_w, const float* __restrict__ out_w,
                          u16* __restrict__ Bt) {
  int t = blockIdx.x;                  // 0..511
  int c = threadIdx.x;                 // 0..255
  const float* W = (t < 256) ? in_w : out_w;
  int tp = t & 255;
  int k, im; float alpha;
  if (tp == 0)      { k = 0;   im = 0; alpha = 1.0f; }
  else if (tp == 1) { k = 128; im = 0; alpha = 1.0f; }
  else              { k = tp >> 1; im = tp & 1; alpha = 2.0f; }
  float scale = alpha * (1.0f / 768.0f);
  float th = -PI2 * (float)k * (1.0f / 256.0f);
  float wr = cosf(th), wi = sinf(th);
  float zr = 1.0f, zi = 0.0f;
  float acc = 0.0f;
  for (int j = 0; j < DD; ++j) {
    float coef = im ? zi : zr;
    acc += coef * W[(size_t)j * DD + c];
    float nzr = zr * wr - zi * wi; zi = zr * wi + zi * wr; zr = nzr;
  }
  Bt[(size_t)c * KP + t] = f2bu(scale * acc);
}

// Bt[c][512+j] = (1/3) sum_k lr[(j+k)%256] * loop_w[k][c]
__global__ void k_build_q(const float* __restrict__ lr, const float* __restrict__ loop_w,
                          u16* __restrict__ Bt) {
  __shared__ float L[DD];
  int j = blockIdx.x, c = threadIdx.x;
  L[c] = lr[c];
  __syncthreads();
  float acc = 0.0f;
  for (int k2 = 0; k2 < DD; ++k2)
    acc += L[(j + k2) & 255] * loop_w[(size_t)k2 * DD + c];
  Bt[(size_t)c * KP + 512 + j] = f2bu(acc * (1.0f / 3.0f));
}

// MFMA DFT, N-fused 128x256: XF = [x;rel] @ Ft^T  -> xfh/rfh (512B rows)
// A is reg-staged from f32 (cvt in regs); converted x-tiles also stored to
// Apack cols 512..767 (each tile converted exactly once).
__global__ __launch_bounds__(512) void k_dft(
    const float* __restrict__ x, const float* __restrict__ rel,
    const u16* __restrict__ Ft, u16* __restrict__ xfh, u16* __restrict__ rfh,
    u16* __restrict__ Ap) {
  __shared__ u16 sA[2][128 * 64];
  __shared__ u16 sB[256 * 64];
  int tid = threadIdx.x;
  int w = tid >> 6, lane = tid & 63;
  int r0 = blockIdx.x * 128;
  int wm = (w & 1) * 64, wn = (w >> 1) * 64;
  int fr = lane & 15, fg = lane >> 4;

  int arow = tid >> 2;                 // 0..127
  int acg = (tid & 3) * 16;            // 16 f32 per thread
  int gr = r0 + arow;
  int grc = gr < MT ? gr : MT - 1;
  const float* asrc = (grc < NN) ? (x + (size_t)grc * DD)
                                 : (rel + (size_t)(grc - NN) * DD);
  bool doAp = (gr < NN);

  float4 a0_, a1_, a2_, a3_;
#define LOADA(kb) { const float* p_ = asrc + (kb) * 64 + acg;                     \
    a0_ = *(const float4*)(p_);     a1_ = *(const float4*)(p_ + 4);               \
    a2_ = *(const float4*)(p_ + 8); a3_ = *(const float4*)(p_ + 12); }

#define STGB(kb) { _Pragma("unroll") for (int q = 0; q < 4; ++q) {                \
    int s_ = w * 4 + q; int c_ = 8 * s_ + (lane >> 3);                            \
    int cb_ = (lane & 7) ^ (c_ & 7);                                              \
    gload16(Ft + (size_t)c_ * 256 + (kb) * 64 + cb_ * 8, sB + s_ * 512); } }

#define CVTA(kb, buf) {                                                           \
    uint4 c0_ = make_uint4(pk2(a0_.x, a0_.y), pk2(a0_.z, a0_.w),                  \
                           pk2(a1_.x, a1_.y), pk2(a1_.z, a1_.w));                 \
    uint4 c1_ = make_uint4(pk2(a2_.x, a2_.y), pk2(a2_.z, a2_.w),                  \
                           pk2(a3_.x, a3_.y), pk2(a3_.z, a3_.w));                 \
    int b0_ = (tid & 3) * 2;                                                      \
    *(uint4*)(sA[buf] + arow * 64 + ((b0_ ^ (arow & 7)) * 8)) = c0_;              \
    *(uint4*)(sA[buf] + arow * 64 + (((b0_ + 1) ^ (arow & 7)) * 8)) = c1_;        \
    if (doAp) { u16* ap_ = Ap + (size_t)gr * KP + 512 + (kb) * 64 + acg;          \
      *(uint4*)(ap_) = c0_; *(uint4*)(ap_ + 8) = c1_; } }

  f32x4 acc[4][4];
#pragma unroll
  for (int i = 0; i < 4; ++i)
#pragma unroll
    for (int j = 0; j < 4; ++j) acc[i][j] = (f32x4){0.f, 0.f, 0.f, 0.f};

  LOADA(0)
  STGB(0)
  CVTA(0, 0)
  LOADA(1)
  __syncthreads();
  for (int kb = 0; kb < 4; ++kb) {
    int cur = kb & 1;
#pragma unroll
    for (int ks = 0; ks < 2; ++ks) {
      bf16x8 af[4], bfr[4];
#pragma unroll
      for (int mt = 0; mt < 4; ++mt) {
        int r = wm + mt * 16 + fr;
        af[mt] = *(const bf16x8*)(sA[cur] + r * 64 + ((ks * 32 + fg * 8) ^ ((r & 7) * 8)));
      }
#pragma unroll
      for (int nt = 0; nt < 4; ++nt) {
        int c = wn + nt * 16 + fr;
        bfr[nt] = *(const bf16x8*)(sB + c * 64 + ((ks * 32 + fg * 8) ^ ((c & 7) * 8)));
      }
#pragma unroll
      for (int mt = 0; mt < 4; ++mt)
#pragma unroll
        for (int nt = 0; nt < 4; ++nt)
          acc[mt][nt] = __builtin_amdgcn_mfma_f32_16x16x32_bf16(af[mt], bfr[nt],
                                                                acc[mt][nt], 0, 0, 0);
    }
    __syncthreads();
    if (kb < 3) {
      STGB(kb + 1)
      CVTA(kb + 1, cur ^ 1)
      if (kb < 2) LOADA(kb + 2)
      __syncthreads();
    }
  }
#undef LOADA
#undef STGB
#undef CVTA

#pragma unroll
  for (int mt = 0; mt < 4; ++mt)
#pragma unroll
    for (int nt = 0; nt < 4; ++nt) {
      int cg = wn + nt * 16 + fr;
#pragma unroll
      for (int j = 0; j < 4; ++j) {
        int rg = r0 + wm + mt * 16 + fg * 4 + j;
        u16 val = f2bu(acc[mt][nt][j]);
        if (rg < NN)      xfh[(size_t)rg * FD + cg] = val;
        else if (rg < MT) rfh[(size_t)(rg - NN) * FD + cg] = val;
      }
    }
}

// ---------- counting sort by key = (e>=EH)*NN + dst ----------
__global__ void k_hist(const int* __restrict__ edst, int* __restrict__ cnt) {
  int e = blockIdx.x * 256 + threadIdx.x;
  int key = edst[e] + ((e >= EH) ? NN : 0);
  atomicAdd(&cnt[key], 1);
}

__global__ __launch_bounds__(256) void k_scan1(const int* __restrict__ cnt,
                                               int* __restrict__ base,
                                               int* __restrict__ chunkTot) {
  __shared__ int wsum[4];
  int t = threadIdx.x;
  int g0 = blockIdx.x * 1024 + t * 4;
  int v[4], ex[4], s = 0;
#pragma unroll
  for (int j = 0; j < 4; ++j) v[j] = (g0 + j < NB) ? cnt[g0 + j] : 0;
#pragma unroll
  for (int j = 0; j < 4; ++j) { ex[j] = s; s += v[j]; }
  int lane = t & 63, w = t >> 6;
  int inc = s;
  for (int off = 1; off < 64; off <<= 1) {
    int n = __shfl_up(inc, off);
    if (lane >= off) inc += n;
  }
  if (lane == 63) wsum[w] = inc;
  __syncthreads();
  int woff = 0;
  for (int i = 0; i < w; ++i) woff += wsum[i];
  int exth = woff + inc - s;
#pragma unroll
  for (int j = 0; j < 4; ++j)
    if (g0 + j < NB) base[g0 + j] = exth + ex[j];
  if (t == 255) chunkTot[blockIdx.x] = woff + inc;
}

__global__ __launch_bounds__(256) void k_scan2(const int* __restrict__ chunkTot,
                                               int* __restrict__ chunkOff) {
  __shared__ int wsum[4];
  int t = threadIdx.x;
  int v = (t < NCH) ? chunkTot[t] : 0;
  int lane = t & 63, w = t >> 6;
  int inc = v;
  for (int off = 1; off < 64; off <<= 1) {
    int n = __shfl_up(inc, off);
    if (lane >= off) inc += n;
  }
  if (lane == 63) wsum[w] = inc;
  __syncthreads();
  int woff = 0;
  for (int i = 0; i < w; ++i) woff += wsum[i];
  if (t < NCH) chunkOff[t] = woff + inc - v;
}

__global__ void k_scan3(int* __restrict__ base, const int* __restrict__ chunkOff,
                        int* __restrict__ cursor) {
  int i = blockIdx.x * 256 + threadIdx.x;
  if (i < NB) {
    int b = base[i] + chunkOff[i >> 10];
    base[i] = b;
    cursor[i] = b;
  }
  if (i == 0) base[NB] = NE;
}

// scatter packed records: (src, typ, norm_bits, 0) -> sorted position
__global__ void k_scatter(const int* __restrict__ esrc, const int* __restrict__ edst,
                          const int* __restrict__ etyp, const float* __restrict__ enorm,
                          int* __restrict__ cursor, int4* __restrict__ recs) {
  int e = blockIdx.x * 256 + threadIdx.x;
  int key = edst[e] + ((e >= EH) ? NN : 0);
  int pos = atomicAdd(&cursor[key], 1);
  recs[pos] = make_int4(esrc[e], etyp[e], __float_as_int(enorm[e]), 0);
}

// one wave per bucket, 4-edge ILP, 512B-aligned rows.
// lane0 pair (cols 0,1) = two REAL bins: product is elementwise.
__global__ __launch_bounds__(256) void k_reduce(
    const u16* __restrict__ xfh, const u16* __restrict__ rfh,
    const int4* __restrict__ recs, const int* __restrict__ base,
    u16* __restrict__ Ap) {
  int w = threadIdx.x >> 6, lane = threadIdx.x & 63;
  int b = blockIdx.x * 4 + w;
  int start = base[b], end = base[b + 1];
  bool l0 = (lane == 0);
  float a0 = 0, a1 = 0, a2 = 0, a3 = 0;
  int p = start;
  for (; p + 3 < end; p += 4) {
    ushort4 xv[4], rv[4];
    float nm[4];
#pragma unroll
    for (int u = 0; u < 4; ++u) {
      int4 rc = recs[p + u];
      nm[u] = __int_as_float(rc.z);
      xv[u] = *(const ushort4*)(xfh + (size_t)rc.x * FD + 4 * lane);
      rv[u] = *(const ushort4*)(rfh + (size_t)rc.y * FD + 4 * lane);
    }
#pragma unroll
    for (int u = 0; u < 4; ++u) {
      float xr0 = bu2f(xv[u].x), xi0 = bu2f(xv[u].y);
      float xr1 = bu2f(xv[u].z), xi1 = bu2f(xv[u].w);
      float rr0 = bu2f(rv[u].x), ri0 = bu2f(rv[u].y);
      float rr1 = bu2f(rv[u].z), ri1 = bu2f(rv[u].w);
      float p0 = l0 ? (xr0 * rr0) : (xr0 * rr0 + xi0 * ri0);
      float p1 = l0 ? (xi0 * ri0) : (xr0 * ri0 - xi0 * rr0);
      a0 += p0 * nm[u];
      a1 += p1 * nm[u];
      a2 += (xr1 * rr1 + xi1 * ri1) * nm[u];
      a3 += (xr1 * ri1 - xi1 * rr1) * nm[u];
    }
  }
  for (; p < end; ++p) {
    int4 rc = recs[p];
    float nm0 = __int_as_float(rc.z);
    ushort4 xv0 = *(const ushort4*)(xfh + (size_t)rc.x * FD + 4 * lane);
    ushort4 rv0 = *(const ushort4*)(rfh + (size_t)rc.y * FD + 4 * lane);
    float xr0 = bu2f(xv0.x), xi0 = bu2f(xv0.y), xr1 = bu2f(xv0.z), xi1 = bu2f(xv0.w);
    float rr0 = bu2f(rv0.x), ri0 = bu2f(rv0.y), rr1 = bu2f(rv0.z), ri1 = bu2f(rv0.w);
    float p0 = l0 ? (xr0 * rr0) : (xr0 * rr0 + xi0 * ri0);
    float p1 = l0 ? (xi0 * ri0) : (xr0 * ri0 - xi0 * rr0);
    a0 += p0 * nm0;
    a1 += p1 * nm0;
    a2 += (xr1 * rr1 + xi1 * ri1) * nm0;
    a3 += (xr1 * ri1 - xi1 * rr1) * nm0;
  }
  u16* tp = Ap + ((b < NN) ? (size_t)b * KP : (size_t)(b - NN) * KP + 256);
  *(unsigned int*)(tp + 4 * lane)     = pk2(a0, a1);
  *(unsigned int*)(tp + 4 * lane + 2) = pk2(a2, a3);
}

// MFMA GEMM, N-fused 128x256: dout = Apack[80000][768] x Bt^T + bias
// sA dbuf (gload) + sB single; fused BN partial sums via shfl + atomics.
__global__ __launch_bounds__(512) void k_mgemm(
    const u16* __restrict__ Ap, const u16* __restrict__ Bt,
    const float* __restrict__ bias, float* __restrict__ dout,
    float* __restrict__ sum1, float* __restrict__ sum2) {
  __shared__ u16 sA[2][128 * 64];
  __shared__ u16 sB[256 * 64];
  int tid = threadIdx.x;
  int w = tid >> 6, lane = tid & 63;
  int r0 = blockIdx.x * 128;
  int wm = (w & 1) * 64, wn = (w >> 1) * 64;
  int fr = lane & 15, fg = lane >> 4;

#define STGA(kb, buf) { _Pragma("unroll") for (int q = 0; q < 2; ++q) {           \
    int s_ = w * 2 + q; int r_ = 8 * s_ + (lane >> 3);                            \
    int cb_ = (lane & 7) ^ (r_ & 7);                                              \
    gload16(Ap + (size_t)(r0 + r_) * KP + (kb) * 64 + cb_ * 8,                    \
            sA[buf] + s_ * 512); } }

#define STGB(kb) { _Pragma("unroll") for (int q = 0; q < 4; ++q) {                \
    int s_ = w * 4 + q; int c_ = 8 * s_ + (lane >> 3);                            \
    int cb_ = (lane & 7) ^ (c_ & 7);                                              \
    gload16(Bt + (size_t)c_ * KP + (kb) * 64 + cb_ * 8, sB + s_ * 512); } }

  f32x4 acc[4][4];
#pragma unroll
  for (int i = 0; i < 4; ++i)
#pragma unroll
    for (int j = 0; j < 4; ++j) acc[i][j] = (f32x4){0.f, 0.f, 0.f, 0.f};

  STGA(0, 0)
  STGB(0)
  __syncthreads();
  for (int kb = 0; kb < 12; ++kb) {
    int cur = kb & 1;
    if (kb < 11) STGA(kb + 1, cur ^ 1)
#pragma unroll
    for (int ks = 0; ks < 2; ++ks) {
      bf16x8 af[4], bfr[4];
#pragma unroll
      for (int mt = 0; mt < 4; ++mt) {
        int r = wm + mt * 16 + fr;
        af[mt] = *(const bf16x8*)(sA[cur] + r * 64 + ((ks * 32 + fg * 8) ^ ((r & 7) * 8)));
      }
#pragma unroll
      for (int nt = 0; nt < 4; ++nt) {
        int c = wn + nt * 16 + fr;
        bfr[nt] = *(const bf16x8*)(sB + c * 64 + ((ks * 32 + fg * 8) ^ ((c & 7) * 8)));
      }
#pragma unroll
      for (int mt = 0; mt < 4; ++mt)
#pragma unroll
        for (int nt = 0; nt < 4; ++nt)
          acc[mt][nt] = __builtin_amdgcn_mfma_f32_16x16x32_bf16(af[mt], bfr[nt],
                                                                acc[mt][nt], 0, 0, 0);
    }
    __syncthreads();
    if (kb < 11) { STGB(kb + 1) __syncthreads(); }
  }
#undef STGA
#undef STGB

  float s1[4] = {0.f, 0.f, 0.f, 0.f}, s2[4] = {0.f, 0.f, 0.f, 0.f};
#pragma unroll
  for (int nt = 0; nt < 4; ++nt) {
    int cg = wn + nt * 16 + fr;
    float bv = bias[cg];
#pragma unroll
    for (int mt = 0; mt < 4; ++mt) {
#pragma unroll
      for (int j = 0; j < 4; ++j) {
        int rg = r0 + wm + mt * 16 + fg * 4 + j;
        float val = acc[mt][nt][j] + bv;
        dout[(size_t)rg * DD + cg] = val;
        s1[nt] += val;
        s2[nt] += val * val;
      }
    }
  }
#pragma unroll
  for (int nt = 0; nt < 4; ++nt) {
    s1[nt] += __shfl_xor(s1[nt], 16); s1[nt] += __shfl_xor(s1[nt], 32);
    s2[nt] += __shfl_xor(s2[nt], 16); s2[nt] += __shfl_xor(s2[nt], 32);
  }
  if (lane < 16) {
#pragma unroll
    for (int nt = 0; nt < 4; ++nt) {
      atomicAdd(&sum1[wn + nt * 16 + lane], s1[nt]);
      atomicAdd(&sum2[wn + nt * 16 + lane], s2[nt]);
    }
  }
}

__global__ void k_stats(const float* __restrict__ sum1, const float* __restrict__ sum2,
                        float* __restrict__ mean, float* __restrict__ rstd) {
  int c = threadIdx.x;
  float m = sum1[c] * (1.0f / (float)NN);
  float var = sum2[c] * (1.0f / (float)NN) - m * m;
  mean[c] = m;
  rstd[c] = rsqrtf(var + 1e-5f);
}

__global__ void k_norm(float* __restrict__ out, const float* __restrict__ mean,
                       const float* __restrict__ rstd) {
  size_t i4 = ((size_t)blockIdx.x * 256 + threadIdx.x) * 4;
  float4* p = (float4*)(out + i4);
  float4 v = *p;
  int c0 = (int)(i4 & 255);
  v.x = (v.x - mean[c0 + 0]) * rstd[c0 + 0];
  v.y = (v.y - mean[c0 + 1]) * rstd[c0 + 1];
  v.z = (v.z - mean[c0 + 2]) * rstd[c0 + 2];
  v.w = (v.w - mean[c0 + 3]) * rstd[c0 + 3];
  *p = v;
}

__global__ void k_rel(const float* __restrict__ rel, const float* __restrict__ wrel,
                      float* __restrict__ out2) {
  __shared__ float R[DD];
  int r = blockIdx.x, c = threadIdx.x;
  R[c] = rel[(size_t)r * DD + c];
  __syncthreads();
  float acc = 0.0f;
  for (int j = 0; j < DD; ++j)
    acc += R[j] * wrel[(size_t)j * DD + c];
  out2[(size_t)r * DD + c] = acc;
}

__global__ void k_fail(float* __restrict__ out, int n) {
  int i = blockIdx.x * 256 + threadIdx.x;
  if (i < n) out[i] = 1.0e6f;   // "workspace too small" marker
}

extern "C" void kernel_launch(void* const* d_in, const int* in_sizes, int n_in,
                              void* d_out, int out_size, void* d_ws, size_t ws_size,
                              hipStream_t stream) {
  (void)in_sizes; (void)n_in;
  const float* x      = (const float*)d_in[0];
  const float* rel    = (const float*)d_in[1];
  const int*   esrc   = (const int*)d_in[2];
  const int*   edst   = (const int*)d_in[3];
  const int*   etyp   = (const int*)d_in[4];
  const float* enorm  = (const float*)d_in[5];
  const float* in_w   = (const float*)d_in[6];
  const float* out_w  = (const float*)d_in[7];
  const float* loop_w = (const float*)d_in[8];
  const float* w_rel  = (const float*)d_in[9];
  const float* lr     = (const float*)d_in[10];
  const float* bias   = (const float*)d_in[11];
  float* dout = (float*)d_out;

  char* wsb = (char*)d_ws;
  size_t off = 0;
  u16* Apack = (u16*)(wsb + off); off += (size_t)NN * KP * 2;        // 122.9 MB
  u16* Bt    = (u16*)(wsb + off); off += (size_t)DD * KP * 2;        // 0.39 MB
  u16* xfh   = (u16*)(wsb + off); off += (size_t)NN * FD * 2;        // 41.0 MB
  u16* rfh   = (u16*)(wsb + off); off += (size_t)NR * FD * 2;        // 0.20 MB
  u16* Ft    = (u16*)(wsb + off); off += (size_t)DD * DD * 2;        // 0.13 MB
  int4* recs = (int4*)(wsb + off); off += (size_t)NE * 16;           // 12.8 MB
  float* sum1  = (float*)(wsb + off); off += DD * 4;
  float* sum2  = (float*)(wsb + off); off += DD * 4;
  float* meanb = (float*)(wsb + off); off += DD * 4;
  float* rstdb = (float*)(wsb + off); off += DD * 4;
  int* cnt   = (int*)(wsb + off); off += (size_t)(NB + 1) * 4;
  int* baseA = (int*)(wsb + off); off += (size_t)(NB + 1) * 4;
  int* curA  = (int*)(wsb + off); off += (size_t)NB * 4;
  int* chT   = (int*)(wsb + off); off += 256 * 4;
  int* chO   = (int*)(wsb + off); off += 256 * 4;

  if (ws_size < off) {
    k_fail<<<(out_size + 255) / 256, 256, 0, stream>>>(dout, out_size);
    return;
  }

  hipMemsetAsync(cnt, 0, (NB + 1) * sizeof(int), stream);
  hipMemsetAsync(sum1, 0, 2 * DD * sizeof(float), stream);
  k_build_f<<<256, 256, 0, stream>>>(Ft);
  k_build_m<<<512, 256, 0, stream>>>(in_w, out_w, Bt);
  k_build_q<<<256, 256, 0, stream>>>(lr, loop_w, Bt);
  k_hist<<<NE / 256, 256, 0, stream>>>(edst, cnt);
  k_scan1<<<NCH, 256, 0, stream>>>(cnt, baseA, chT);
  k_scan2<<<1, 256, 0, stream>>>(chT, chO);
  k_scan3<<<(NB + 255) / 256, 256, 0, stream>>>(baseA, chO, curA);
  k_scatter<<<NE / 256, 256, 0, stream>>>(esrc, edst, etyp, enorm, curA, recs);
  k_dft<<<(MT + 127) / 128, 512, 0, stream>>>(x, rel, Ft, xfh, rfh, Apack);
  k_reduce<<<NB / 4, 256, 0, stream>>>(xfh, rfh, recs, baseA, Apack);
  k_mgemm<<<NN / 128, 512, 0, stream>>>(Apack, Bt, bias, dout, sum1, sum2);
  k_stats<<<1, 256, 0, stream>>>(sum1, sum2, meanb, rstdb);
  k_norm<<<NN * DD / 4 / 256, 256, 0, stream>>>(dout, meanb, rstdb);
  k_rel<<<NR, 256, 0, stream>>>(rel, w_rel, dout + (size_t)NN * DD);
}